// Round 12
// baseline (223.463 us; speedup 1.0000x reference)
//
#include <hip/hip_runtime.h>
#include <math.h>

// SensorGNN: 2-layer GCN (N=50000, E=800000, F=128, H=64) + flat classifier (6 classes).
// Graph build = counting sort by dst-range: hist_ranges -> scatter_ranges(folded scan) ->
//   csr_range(folded prefix; dinv/offs/splits/srt).
// Per layer: gemm+dinv->bf16 G, then 2-PHASE aggregation:
//   phase0: self(NT) + gather src<NHALF (3.2MB slab, L2-resident) -> NT raw sums in H
//   phase1: NT raw + gather src>=NHALF -> epilogue (layer1: relu->H; layer2: fused classifier)
// All streaming traffic (self rows, H, srt, Wc) is NONTEMPORAL so only the gather slab
// allocates in L2.
// r3: same-line global atomics serialize cross-XCD. r4/5: random atomic scatter bounces
// lines via HBM. r6: edge replication = occupancy loss. r7/8: gather ILP-invariant.
// r9: bytes sub-linear. r11 counters: FETCH=104MB/agg = EVERY gather misses L2 (6.4MB>4MB).
// r10 failed from L2 pollution by self/H/srt streams -> NT protection is the missing piece.

#define NCH 256          // edge chunk blocks
#define RBITS 10         // range = 1024 nodes
#define NR_MAX 64

typedef float  f32x4 __attribute__((ext_vector_type(4)));
typedef unsigned short u16x4 __attribute__((ext_vector_type(4)));

__device__ __forceinline__ ushort f32_to_bf16(float f) {  // RTN-even
  unsigned u = __float_as_uint(f);
  return (ushort)((u + 0x7fffu + ((u >> 16) & 1u)) >> 16);
}
__device__ __forceinline__ float bf16_to_f32(ushort h) {
  return __uint_as_float(((unsigned)h) << 16);
}
__device__ __forceinline__ float4 nt_ld_f4(const float* p) {
  f32x4 v = __builtin_nontemporal_load((const f32x4*)p);
  return make_float4(v.x, v.y, v.z, v.w);
}
__device__ __forceinline__ void nt_st_f4(float* p, float4 a) {
  f32x4 v; v.x = a.x; v.y = a.y; v.z = a.z; v.w = a.w;
  __builtin_nontemporal_store(v, (f32x4*)p);
}
__device__ __forceinline__ ushort4 nt_ld_u4(const ushort* p) {
  u16x4 v = __builtin_nontemporal_load((const u16x4*)p);
  ushort4 r; r.x = v.x; r.y = v.y; r.z = v.z; r.w = v.w;
  return r;
}
__device__ __forceinline__ int nt_ld_i(const int* p) {
  return __builtin_nontemporal_load(p);
}

// ---------------- pass A: per-chunk range histograms (raw counts) ----------------

__global__ __launch_bounds__(256) void hist_ranges(
    const int* __restrict__ dst, int* __restrict__ ghist, int NR, int E) {
  __shared__ int h[NR_MAX];
  int tid = threadIdx.x, c = blockIdx.x;
  if (tid < NR) h[tid] = 0;
  __syncthreads();
  int E4 = E >> 2;
  int CH4 = (E4 + NCH - 1) / NCH;
  int i0 = c * CH4, i1 = min(i0 + CH4, E4);
  const int4* d4 = (const int4*)dst;
  for (int i = i0 + tid; i < i1; i += 256) {
    int4 d = d4[i];
    atomicAdd(&h[d.x >> RBITS], 1);
    atomicAdd(&h[d.y >> RBITS], 1);
    atomicAdd(&h[d.z >> RBITS], 1);
    atomicAdd(&h[d.w >> RBITS], 1);
  }
  if (c == NCH - 1) {
    for (int e = (E4 << 2) + tid; e < E; e += 256) atomicAdd(&h[dst[e] >> RBITS], 1);
  }
  __syncthreads();
  if (tid < NR) ghist[tid * NCH + c] = h[tid];  // range-major, chunk-minor (raw counts)
}

// ---------------- pass B: scatter with per-block folded prefix scan ----------------

__global__ __launch_bounds__(256) void scatter_ranges(
    const int* __restrict__ src, const int* __restrict__ dst,
    const int* __restrict__ ghist, int2* __restrict__ ebuf, int NR, int E) {
  __shared__ int cur[NR_MAX];
  __shared__ int rowpre[NR_MAX + 1];
  int tid = threadIdx.x, c = blockIdx.x;
  if (tid < NR) {  // row totals (vectorized over 50KB L2-hot hist)
    const int4* row = (const int4*)(ghist + tid * NCH);
    int s = 0;
    for (int q = 0; q < NCH / 4; ++q) { int4 v = row[q]; s += v.x + v.y + v.z + v.w; }
    rowpre[tid + 1] = s;
  }
  __syncthreads();
  if (tid == 0) {
    rowpre[0] = 0;
    for (int i = 1; i <= NR; ++i) rowpre[i] += rowpre[i - 1];
  }
  __syncthreads();
  if (tid < NR) {  // + chunks < c within own row
    int s = rowpre[tid];
    const int* row = ghist + tid * NCH;
    const int4* row4 = (const int4*)row;
    int c4 = c >> 2;
    for (int q = 0; q < c4; ++q) { int4 v = row4[q]; s += v.x + v.y + v.z + v.w; }
    for (int cc = c4 << 2; cc < c; ++cc) s += row[cc];
    cur[tid] = s;
  }
  __syncthreads();
  int E4 = E >> 2;
  int CH4 = (E4 + NCH - 1) / NCH;
  int i0 = c * CH4, i1 = min(i0 + CH4, E4);
  const int4* d4 = (const int4*)dst;
  const int4* s4 = (const int4*)src;
  for (int i = i0 + tid; i < i1; i += 256) {
    int4 d = d4[i];
    int4 s = s4[i];
    ebuf[atomicAdd(&cur[d.x >> RBITS], 1)] = make_int2(s.x, d.x);
    ebuf[atomicAdd(&cur[d.y >> RBITS], 1)] = make_int2(s.y, d.y);
    ebuf[atomicAdd(&cur[d.z >> RBITS], 1)] = make_int2(s.z, d.z);
    ebuf[atomicAdd(&cur[d.w >> RBITS], 1)] = make_int2(s.w, d.w);
  }
  if (c == NCH - 1) {
    for (int e = (E4 << 2) + tid; e < E; e += 256)
      ebuf[atomicAdd(&cur[dst[e] >> RBITS], 1)] = make_int2(src[e], dst[e]);
  }
}

// ---------------- pass C: per-range CSR build with src-half split ----------------
// srt layout per node: [offs[n], splits[n]) = src<NHALF, [splits[n], offs[n+1]) = rest.

__global__ __launch_bounds__(1024) void csr_range(
    const int2* __restrict__ ebuf, const int* __restrict__ ghist,
    int* __restrict__ offs, int* __restrict__ splits, int* __restrict__ srt,
    float* __restrict__ dinv, int N, int E, int NR, int NHALF) {
  __shared__ int hT[1024];  // total counts -> low cursor
  __shared__ int hL[1024];  // low-half counts -> high cursor
  __shared__ int wtot[16];
  __shared__ int rowpre[NR_MAX + 1];
  int r = blockIdx.x;
  int lo = r << RBITS;
  int len = min(1024, N - lo);
  int tid = threadIdx.x, lane = tid & 63, wv = tid >> 6;
  // folded prefix: segment bounds from raw ghist
  if (tid < NR) {
    const int4* row = (const int4*)(ghist + tid * NCH);
    int s = 0;
    for (int q = 0; q < NCH / 4; ++q) { int4 v = row[q]; s += v.x + v.y + v.z + v.w; }
    rowpre[tid + 1] = s;
  }
  if (tid < len) { hT[tid] = 0; hL[tid] = 0; }
  __syncthreads();
  if (tid == 0) {
    rowpre[0] = 0;
    for (int i = 1; i <= NR; ++i) rowpre[i] += rowpre[i - 1];
  }
  __syncthreads();
  int S = rowpre[r], S1 = rowpre[r + 1];
  for (int i = S + tid; i < S1; i += 1024) {
    int2 e = ebuf[i];
    atomicAdd(&hT[e.y - lo], 1);
    if (e.x < NHALF) atomicAdd(&hL[e.y - lo], 1);
  }
  __syncthreads();
  int v = (tid < len) ? hT[tid] : 0;
  if (tid < len) dinv[lo + tid] = rsqrtf((float)(v + 1));  // +1 self loop
  // exclusive scan of v across 1024 threads
  int x = v;
#pragma unroll
  for (int d = 1; d < 64; d <<= 1) { int y = __shfl_up(x, d, 64); if (lane >= d) x += y; }
  if (lane == 63) wtot[wv] = x;
  __syncthreads();
  if (wv == 0 && lane < 16) {
    int t = wtot[lane], xx = t;
#pragma unroll
    for (int d = 1; d < 16; d <<= 1) { int y = __shfl_up(xx, d, 64); if (lane >= d) xx += y; }
    wtot[lane] = xx - t;
  }
  __syncthreads();
  int excl = x - v + wtot[wv];
  if (tid < len) {
    int base = S + excl;
    int sp = base + hL[tid];   // own-thread read before overwrite
    offs[lo + tid] = base;
    splits[lo + tid] = sp;
    hT[tid] = base;            // low-half cursor
    hL[tid] = sp;              // high-half cursor
  }
  if (r == 0 && tid == 0) offs[N] = E;
  __syncthreads();
  for (int i = S + tid; i < S1; i += 1024) {
    int2 e = ebuf[i];
    int idx = e.y - lo;
    int p = (e.x < NHALF) ? atomicAdd(&hT[idx], 1) : atomicAdd(&hL[idx], 1);
    srt[p] = e.x;
  }
}

// ---------------- dense transform: Gb = bf16((X @ W) * dinv[row]) ----------------
// Unroll capped at 4 to avoid the round-1 VGPR blowup (256 VGPR + 380MB scratch spill).

template <int K, int ROWS>
__global__ __launch_bounds__(256) void gemm_scale(
    const float* __restrict__ X, const float* __restrict__ W,
    const float* __restrict__ dinv, ushort* __restrict__ Gb, int N) {
  __shared__ float smw[K * 64];
  __shared__ float xs[ROWS * K];
  int tid = threadIdx.x, lane = tid & 63, wv = tid >> 6;
  for (int idx = tid; idx < K * 16; idx += 256)
    ((float4*)smw)[idx] = ((const float4*)W)[idx];
  int row0 = blockIdx.x * ROWS;
  int base = row0 * K;
  int cnt4 = (min(ROWS * K, N * K - base)) >> 2;  // K%4==0 so exact
  const float4* X4 = (const float4*)(X + base);
  for (int idx = tid; idx < cnt4; idx += 256) ((float4*)xs)[idx] = X4[idx];
  __syncthreads();

  constexpr int RW = ROWS / 4;  // rows per wave
  float acc[RW];
#pragma unroll
  for (int r = 0; r < RW; ++r) acc[r] = 0.f;
  const float* xr = &xs[(wv * RW) * K];
#pragma unroll 4
  for (int k = 0; k < K; ++k) {
    float wval = smw[k * 64 + lane];  // lane-contiguous: 2-way bank alias = free
#pragma unroll
    for (int r = 0; r < RW; ++r) acc[r] = fmaf(xr[r * K + k], wval, acc[r]);  // LDS broadcast
  }
#pragma unroll
  for (int r = 0; r < RW; ++r) {
    int row = row0 + wv * RW + r;
    if (row < N) Gb[(size_t)row * 64 + lane] = f32_to_bf16(acc[r] * dinv[row]);
  }
}

// ---------------- 2-phase aggregation (+ fused classifier in final phase) ----------------
// one wave per node; lane = sub*16 + fl; indices hoisted to regs + dynamic shfl;
// 8 bf16 rows (2 lines) in flight. Gather loads are NORMAL (want L2 allocate);
// everything else (self row, H raw, srt, offs/splits, Wc) is NONTEMPORAL.
// PHASE 0: acc = self + sum(src<NHALF);  NT-store raw float4 sums to H.
// PHASE 1: acc = NT(H raw) + sum(src>=NHALF); CLS=0: H=relu(acc*dinv+b);
//          CLS=1: fused classifier dot -> part[blk][6] (h never stored).

template <int PHASE, int CLS>
__global__ __launch_bounds__(256) void aggregate(
    const ushort* __restrict__ Gb, const int* __restrict__ offs,
    const int* __restrict__ splits, const int* __restrict__ srt,
    const float* __restrict__ dinv, const float* __restrict__ bias,
    const float* __restrict__ Wc, float* __restrict__ H,
    float* __restrict__ part, int N) {
  int lane = threadIdx.x & 63, wv = threadIdx.x >> 6;
  int sub = lane >> 4, fl = lane & 15;
  int node = blockIdx.x * 4 + wv;
  const ushort4* G2 = (const ushort4*)Gb;  // 16 x ushort4 per 64-feat row

  if (!(PHASE == 1 && CLS == 1) && node >= N) return;  // CLS block-reduce needs all threads

  int e0 = 0, e1 = 0;
  if (node < N) {
    if (PHASE == 0) { e0 = nt_ld_i(&offs[node]); e1 = nt_ld_i(&splits[node]); }
    else            { e0 = nt_ld_i(&splits[node]); e1 = nt_ld_i(&offs[node + 1]); }
  }
  int deg = e1 - e0;

  float4 accA = make_float4(0.f, 0.f, 0.f, 0.f);
  float4 accB = make_float4(0.f, 0.f, 0.f, 0.f);
  if (sub == 0 && node < N) {
    if (PHASE == 0) {  // self loop: NT (sequential stream, don't evict slab)
      ushort4 q = nt_ld_u4(&Gb[((size_t)node * 16 + fl) * 4]);
      accA.x = bf16_to_f32(q.x); accA.y = bf16_to_f32(q.y);
      accA.z = bf16_to_f32(q.z); accA.w = bf16_to_f32(q.w);
    } else {           // raw sums from phase 0: NT
      accA = nt_ld_f4(&H[((size_t)node * 16 + fl) * 4]);
    }
  }

  // hoist up to 64 edge indices into registers (coalesced, NT)
  int pre = (deg > 0) ? nt_ld_i(&srt[e0 + min(lane, deg - 1)]) : 0;

  int dcap = min(deg, 64);
  int base = 0;
  for (; base + 7 < dcap; base += 8) {   // 8 rows in flight, no index-load chain
    int sA = __shfl(pre, base + sub, 64);
    int sB = __shfl(pre, base + 4 + sub, 64);
    ushort4 qA = G2[(size_t)sA * 16 + fl];
    ushort4 qB = G2[(size_t)sB * 16 + fl];
    accA.x += bf16_to_f32(qA.x); accA.y += bf16_to_f32(qA.y);
    accA.z += bf16_to_f32(qA.z); accA.w += bf16_to_f32(qA.w);
    accB.x += bf16_to_f32(qB.x); accB.y += bf16_to_f32(qB.y);
    accB.z += bf16_to_f32(qB.z); accB.w += bf16_to_f32(qB.w);
  }
  for (; base + 3 < dcap; base += 4) {
    int s = __shfl(pre, base + sub, 64);
    ushort4 q = G2[(size_t)s * 16 + fl];
    accA.x += bf16_to_f32(q.x); accA.y += bf16_to_f32(q.y);
    accA.z += bf16_to_f32(q.z); accA.w += bf16_to_f32(q.w);
  }
  int e = e0 + base;
  for (; e + 3 < e1; e += 4) {           // deg>64 spillover (rare)
    int s = nt_ld_i(&srt[e + sub]);
    ushort4 q = G2[(size_t)s * 16 + fl];
    accA.x += bf16_to_f32(q.x); accA.y += bf16_to_f32(q.y);
    accA.z += bf16_to_f32(q.z); accA.w += bf16_to_f32(q.w);
  }
  int rem = e1 - e;                      // 0..3 remainder
  if (sub < rem) {
    int s = nt_ld_i(&srt[e + sub]);
    ushort4 q = G2[(size_t)s * 16 + fl];
    accA.x += bf16_to_f32(q.x); accA.y += bf16_to_f32(q.y);
    accA.z += bf16_to_f32(q.z); accA.w += bf16_to_f32(q.w);
  }

  float4 acc;
  acc.x = accA.x + accB.x; acc.y = accA.y + accB.y;
  acc.z = accA.z + accB.z; acc.w = accA.w + accB.w;
#pragma unroll
  for (int m = 16; m < 64; m <<= 1) {
    acc.x += __shfl_xor(acc.x, m, 64);
    acc.y += __shfl_xor(acc.y, m, 64);
    acc.z += __shfl_xor(acc.z, m, 64);
    acc.w += __shfl_xor(acc.w, m, 64);
  }

  if (PHASE == 0) {
    if (sub == 0 && node < N)
      nt_st_f4(&H[((size_t)node * 16 + fl) * 4], acc);  // raw partial sums
  } else if (CLS == 0) {
    if (sub == 0 && node < N) {
      float dn = dinv[node];
      float4 bb = ((const float4*)bias)[fl];
      float4 r;
      r.x = fmaxf(fmaf(acc.x, dn, bb.x), 0.f);
      r.y = fmaxf(fmaf(acc.y, dn, bb.y), 0.f);
      r.z = fmaxf(fmaf(acc.z, dn, bb.z), 0.f);
      r.w = fmaxf(fmaf(acc.w, dn, bb.w), 0.f);
      nt_st_f4(&H[((size_t)node * 16 + fl) * 4], r);
    }
  } else {
    float a[6] = {0.f, 0.f, 0.f, 0.f, 0.f, 0.f};
    if (sub == 0 && node < N) {
      float dn = dinv[node];
      float4 bb = ((const float4*)bias)[fl];
      float4 r;
      r.x = fmaxf(fmaf(acc.x, dn, bb.x), 0.f);
      r.y = fmaxf(fmaf(acc.y, dn, bb.y), 0.f);
      r.z = fmaxf(fmaf(acc.z, dn, bb.z), 0.f);
      r.w = fmaxf(fmaf(acc.w, dn, bb.w), 0.f);
      // Wc slice for feats 4fl..4fl+3 of this node: 24 contiguous floats, NT
      const float* wp = Wc + (size_t)node * 384 + fl * 24;
      float4 w0 = nt_ld_f4(wp), w1 = nt_ld_f4(wp + 4), w2 = nt_ld_f4(wp + 8);
      float4 w3 = nt_ld_f4(wp + 12), w4_ = nt_ld_f4(wp + 16), w5 = nt_ld_f4(wp + 20);
      // layout: [f0c0..f0c5 f1c0..f1c5 f2c0..f2c5 f3c0..f3c5]
      a[0] = fmaf(r.x, w0.x, fmaf(r.y, w1.z, fmaf(r.z, w3.x, r.w * w4_.z)));
      a[1] = fmaf(r.x, w0.y, fmaf(r.y, w1.w, fmaf(r.z, w3.y, r.w * w4_.w)));
      a[2] = fmaf(r.x, w0.z, fmaf(r.y, w2.x, fmaf(r.z, w3.z, r.w * w5.x)));
      a[3] = fmaf(r.x, w0.w, fmaf(r.y, w2.y, fmaf(r.z, w3.w, r.w * w5.y)));
      a[4] = fmaf(r.x, w1.x, fmaf(r.y, w2.z, fmaf(r.z, w4_.x, r.w * w5.z)));
      a[5] = fmaf(r.x, w1.y, fmaf(r.y, w2.w, fmaf(r.z, w4_.y, r.w * w5.w)));
    }
#pragma unroll
    for (int c = 0; c < 6; ++c) {
      for (int d = 32; d > 0; d >>= 1) a[c] += __shfl_down(a[c], d, 64);
    }
    __shared__ float sh[4][6];
    if (lane == 0) {
#pragma unroll
      for (int c = 0; c < 6; ++c) sh[wv][c] = a[c];
    }
    __syncthreads();
    if (threadIdx.x == 0) {
#pragma unroll
      for (int c = 0; c < 6; ++c)
        part[(size_t)blockIdx.x * 6 + c] = sh[0][c] + sh[1][c] + sh[2][c] + sh[3][c];
    }
  }
}

// single block: sum part[nb][6], add bias, softmax, write out[6]
__global__ __launch_bounds__(1024) void reduce_softmax(
    const float* __restrict__ part, int nb,
    const float* __restrict__ bc, float* __restrict__ out) {
  int tid = threadIdx.x, lane = tid & 63, wv = tid >> 6;
  float a[6] = {0.f, 0.f, 0.f, 0.f, 0.f, 0.f};
  for (int b = tid; b < nb; b += 1024) {
    const float* p = part + (size_t)b * 6;
#pragma unroll
    for (int c = 0; c < 6; ++c) a[c] += p[c];
  }
#pragma unroll
  for (int c = 0; c < 6; ++c) {
    for (int d = 32; d > 0; d >>= 1) a[c] += __shfl_down(a[c], d, 64);
  }
  __shared__ float sh[16][6];
  if (lane == 0) {
#pragma unroll
    for (int c = 0; c < 6; ++c) sh[wv][c] = a[c];
  }
  __syncthreads();
  if (tid == 0) {
    float l[6], m = -1e30f;
#pragma unroll
    for (int c = 0; c < 6; ++c) {
      float t = 0.f;
      for (int w = 0; w < 16; ++w) t += sh[w][c];
      l[c] = t + bc[c];
      m = fmaxf(m, l[c]);
    }
    float s = 0.f;
#pragma unroll
    for (int c = 0; c < 6; ++c) { l[c] = __expf(l[c] - m); s += l[c]; }
    float inv = 1.f / s;
#pragma unroll
    for (int c = 0; c < 6; ++c) out[c] = l[c] * inv;
  }
}

// ---------------- launch ----------------

static inline size_t align4up(size_t x) { return (x + 3) & ~(size_t)3; }  // 4-elem = 16B

extern "C" void kernel_launch(void* const* d_in, const int* in_sizes, int n_in,
                              void* d_out, int out_size, void* d_ws, size_t ws_size,
                              hipStream_t stream) {
  const float* x  = (const float*)d_in[0];
  const int*   ei = (const int*)d_in[1];
  const float* W1 = (const float*)d_in[2];
  const float* b1 = (const float*)d_in[3];
  const float* W2 = (const float*)d_in[4];
  const float* b2 = (const float*)d_in[5];
  const float* Wc = (const float*)d_in[6];
  const float* bc = (const float*)d_in[7];
  float* out = (float*)d_out;

  const int N = in_sizes[0] / 128;  // 50000
  const int E = in_sizes[1] / 2;    // 800000
  const int* esrc = ei;
  const int* edst = ei + E;
  const int NR = (N + 1023) >> RBITS;  // 49 ranges (<= NR_MAX)
  const int AGRID = (N + 3) / 4;       // 12500 aggregate blocks
  const int NHALF = N / 2;             // 25000: src-half split (3.2MB bf16 slab per phase)

  // 16B-aligned workspace carve
  size_t o = 0;
  int* offs   = (int*)d_ws + o;           o = align4up(o + N + 1);
  int* splits = (int*)d_ws + o;           o = align4up(o + N);
  int* srt    = (int*)d_ws + o;           o = align4up(o + E);
  float* dinv = (float*)d_ws + o;         o = align4up(o + N);
  int* ghist  = (int*)d_ws + o;           o = align4up(o + (size_t)NR * NCH);
  ushort* Gb  = (ushort*)((int*)d_ws + o); o = align4up(o + (size_t)N * 32);  // N*64 bf16
  float* bufB = (float*)d_ws + o;         o = align4up(o + (size_t)N * 64);
  float* part = (float*)d_ws + o;         o = align4up(o + (size_t)AGRID * 6);
  int2* ebuf  = (int2*)bufB;  // aliases bufB: dead after csr_range, bufB written by agg phase0

  hist_ranges<<<NCH, 256, 0, stream>>>(edst, ghist, NR, E);
  scatter_ranges<<<NCH, 256, 0, stream>>>(esrc, edst, ghist, ebuf, NR, E);
  csr_range<<<NR, 1024, 0, stream>>>(ebuf, ghist, offs, splits, srt, dinv, N, E, NR, NHALF);

  gemm_scale<128, 32><<<(N + 31) / 32, 256, 0, stream>>>(x, W1, dinv, Gb, N);
  aggregate<0, 0><<<AGRID, 256, 0, stream>>>(Gb, offs, splits, srt, dinv, b1, nullptr, bufB, nullptr, N);
  aggregate<1, 0><<<AGRID, 256, 0, stream>>>(Gb, offs, splits, srt, dinv, b1, nullptr, bufB, nullptr, N);
  gemm_scale<64, 32><<<(N + 31) / 32, 256, 0, stream>>>(bufB, W2, dinv, Gb, N);
  aggregate<0, 0><<<AGRID, 256, 0, stream>>>(Gb, offs, splits, srt, dinv, b2, nullptr, bufB, nullptr, N);
  aggregate<1, 1><<<AGRID, 256, 0, stream>>>(Gb, offs, splits, srt, dinv, b2, Wc, bufB, part, N);

  reduce_softmax<<<1, 1024, 0, stream>>>(part, AGRID, bc, out);
}

// Round 13
// 165.111 us; speedup vs baseline: 1.3534x; 1.3534x over previous
//
#include <hip/hip_runtime.h>
#include <math.h>

// SensorGNN: 2-layer GCN (N=50000, E=800000, F=128, H=64) + flat classifier (6 classes).
// Graph build = counting sort by dst-range: hist_ranges -> scatter_ranges(folded scan) ->
//   csr_range(folded prefix; dinv/offs/srt).
// Per layer: gemm+dinv->bf16 G -> single-pass aggregate (layer2 fuses classifier).
// r3: same-line global atomics serialize cross-XCD. r4/5: random atomic scatter bounces
// lines via HBM. r6: edge replication = occupancy loss. r7/8: gather ILP-invariant.
// r9: bytes sub-linear. r11: FETCH=104MB/agg (every gather misses 4MB L2).
// r12 (decisive): HALF the gathers took the SAME 49us -> aggregate is bound by the
//   per-node serial miss chain (offs -> srt -> gathers), not gather throughput.
// r13 fix: 4 nodes per wave -- one coalesced offs load, 4 independent srt hoists,
//   cross-node interleaved gathers (4 chains overlapped).

#define NCH 256          // edge chunk blocks
#define RBITS 10         // range = 1024 nodes
#define NR_MAX 64

__device__ __forceinline__ ushort f32_to_bf16(float f) {  // RTN-even
  unsigned u = __float_as_uint(f);
  return (ushort)((u + 0x7fffu + ((u >> 16) & 1u)) >> 16);
}
__device__ __forceinline__ float bf16_to_f32(ushort h) {
  return __uint_as_float(((unsigned)h) << 16);
}

// ---------------- pass A: per-chunk range histograms (raw counts) ----------------

__global__ __launch_bounds__(256) void hist_ranges(
    const int* __restrict__ dst, int* __restrict__ ghist, int NR, int E) {
  __shared__ int h[NR_MAX];
  int tid = threadIdx.x, c = blockIdx.x;
  if (tid < NR) h[tid] = 0;
  __syncthreads();
  int E4 = E >> 2;
  int CH4 = (E4 + NCH - 1) / NCH;
  int i0 = c * CH4, i1 = min(i0 + CH4, E4);
  const int4* d4 = (const int4*)dst;
  for (int i = i0 + tid; i < i1; i += 256) {
    int4 d = d4[i];
    atomicAdd(&h[d.x >> RBITS], 1);
    atomicAdd(&h[d.y >> RBITS], 1);
    atomicAdd(&h[d.z >> RBITS], 1);
    atomicAdd(&h[d.w >> RBITS], 1);
  }
  if (c == NCH - 1) {
    for (int e = (E4 << 2) + tid; e < E; e += 256) atomicAdd(&h[dst[e] >> RBITS], 1);
  }
  __syncthreads();
  if (tid < NR) ghist[tid * NCH + c] = h[tid];  // range-major, chunk-minor (raw counts)
}

// ---------------- pass B: scatter with per-block folded prefix scan ----------------

__global__ __launch_bounds__(256) void scatter_ranges(
    const int* __restrict__ src, const int* __restrict__ dst,
    const int* __restrict__ ghist, int2* __restrict__ ebuf, int NR, int E) {
  __shared__ int cur[NR_MAX];
  __shared__ int rowpre[NR_MAX + 1];
  int tid = threadIdx.x, c = blockIdx.x;
  if (tid < NR) {  // row totals (vectorized over 50KB L2-hot hist)
    const int4* row = (const int4*)(ghist + tid * NCH);
    int s = 0;
    for (int q = 0; q < NCH / 4; ++q) { int4 v = row[q]; s += v.x + v.y + v.z + v.w; }
    rowpre[tid + 1] = s;
  }
  __syncthreads();
  if (tid == 0) {
    rowpre[0] = 0;
    for (int i = 1; i <= NR; ++i) rowpre[i] += rowpre[i - 1];
  }
  __syncthreads();
  if (tid < NR) {  // + chunks < c within own row
    int s = rowpre[tid];
    const int* row = ghist + tid * NCH;
    const int4* row4 = (const int4*)row;
    int c4 = c >> 2;
    for (int q = 0; q < c4; ++q) { int4 v = row4[q]; s += v.x + v.y + v.z + v.w; }
    for (int cc = c4 << 2; cc < c; ++cc) s += row[cc];
    cur[tid] = s;
  }
  __syncthreads();
  int E4 = E >> 2;
  int CH4 = (E4 + NCH - 1) / NCH;
  int i0 = c * CH4, i1 = min(i0 + CH4, E4);
  const int4* d4 = (const int4*)dst;
  const int4* s4 = (const int4*)src;
  for (int i = i0 + tid; i < i1; i += 256) {
    int4 d = d4[i];
    int4 s = s4[i];
    ebuf[atomicAdd(&cur[d.x >> RBITS], 1)] = make_int2(s.x, d.x);
    ebuf[atomicAdd(&cur[d.y >> RBITS], 1)] = make_int2(s.y, d.y);
    ebuf[atomicAdd(&cur[d.z >> RBITS], 1)] = make_int2(s.z, d.z);
    ebuf[atomicAdd(&cur[d.w >> RBITS], 1)] = make_int2(s.w, d.w);
  }
  if (c == NCH - 1) {
    for (int e = (E4 << 2) + tid; e < E; e += 256)
      ebuf[atomicAdd(&cur[dst[e] >> RBITS], 1)] = make_int2(src[e], dst[e]);
  }
}

// ---------------- pass C: per-range CSR build (dinv, offs, srt) ----------------

__global__ __launch_bounds__(1024) void csr_range(
    const int2* __restrict__ ebuf, const int* __restrict__ ghist,
    int* __restrict__ offs, int* __restrict__ srt, float* __restrict__ dinv,
    int N, int E, int NR) {
  __shared__ int hist[1024];
  __shared__ int wtot[16];
  __shared__ int rowpre[NR_MAX + 1];
  int r = blockIdx.x;
  int lo = r << RBITS;
  int len = min(1024, N - lo);
  int tid = threadIdx.x, lane = tid & 63, wv = tid >> 6;
  if (tid < NR) {
    const int4* row = (const int4*)(ghist + tid * NCH);
    int s = 0;
    for (int q = 0; q < NCH / 4; ++q) { int4 v = row[q]; s += v.x + v.y + v.z + v.w; }
    rowpre[tid + 1] = s;
  }
  if (tid < len) hist[tid] = 0;
  __syncthreads();
  if (tid == 0) {
    rowpre[0] = 0;
    for (int i = 1; i <= NR; ++i) rowpre[i] += rowpre[i - 1];
  }
  __syncthreads();
  int S = rowpre[r], S1 = rowpre[r + 1];
  for (int i = S + tid; i < S1; i += 1024) atomicAdd(&hist[ebuf[i].y - lo], 1);
  __syncthreads();
  int v = (tid < len) ? hist[tid] : 0;
  if (tid < len) dinv[lo + tid] = rsqrtf((float)(v + 1));  // +1 self loop
  // exclusive scan of v across 1024 threads
  int x = v;
#pragma unroll
  for (int d = 1; d < 64; d <<= 1) { int y = __shfl_up(x, d, 64); if (lane >= d) x += y; }
  if (lane == 63) wtot[wv] = x;
  __syncthreads();
  if (wv == 0 && lane < 16) {
    int t = wtot[lane], xx = t;
#pragma unroll
    for (int d = 1; d < 16; d <<= 1) { int y = __shfl_up(xx, d, 64); if (lane >= d) xx += y; }
    wtot[lane] = xx - t;
  }
  __syncthreads();
  int excl = x - v + wtot[wv];
  if (tid < len) {
    offs[lo + tid] = S + excl;
    hist[tid] = S + excl;  // reuse as cursor
  }
  if (r == 0 && tid == 0) offs[N] = E;
  __syncthreads();
  for (int i = S + tid; i < S1; i += 1024) {
    int2 e = ebuf[i];
    srt[atomicAdd(&hist[e.y - lo], 1)] = e.x;
  }
}

// ---------------- dense transform: Gb = bf16((X @ W) * dinv[row]) ----------------
// Unroll capped at 4 to avoid the round-1 VGPR blowup (256 VGPR + 380MB scratch spill).

template <int K, int ROWS>
__global__ __launch_bounds__(256) void gemm_scale(
    const float* __restrict__ X, const float* __restrict__ W,
    const float* __restrict__ dinv, ushort* __restrict__ Gb, int N) {
  __shared__ float smw[K * 64];
  __shared__ float xs[ROWS * K];
  int tid = threadIdx.x, lane = tid & 63, wv = tid >> 6;
  for (int idx = tid; idx < K * 16; idx += 256)
    ((float4*)smw)[idx] = ((const float4*)W)[idx];
  int row0 = blockIdx.x * ROWS;
  int base = row0 * K;
  int cnt4 = (min(ROWS * K, N * K - base)) >> 2;  // K%4==0 so exact
  const float4* X4 = (const float4*)(X + base);
  for (int idx = tid; idx < cnt4; idx += 256) ((float4*)xs)[idx] = X4[idx];
  __syncthreads();

  constexpr int RW = ROWS / 4;  // rows per wave
  float acc[RW];
#pragma unroll
  for (int r = 0; r < RW; ++r) acc[r] = 0.f;
  const float* xr = &xs[(wv * RW) * K];
#pragma unroll 4
  for (int k = 0; k < K; ++k) {
    float wval = smw[k * 64 + lane];  // lane-contiguous: 2-way bank alias = free
#pragma unroll
    for (int r = 0; r < RW; ++r) acc[r] = fmaf(xr[r * K + k], wval, acc[r]);  // LDS broadcast
  }
#pragma unroll
  for (int r = 0; r < RW; ++r) {
    int row = row0 + wv * RW + r;
    if (row < N) Gb[(size_t)row * 64 + lane] = f32_to_bf16(acc[r] * dinv[row]);
  }
}

// ---------------- aggregation: 4 NODES PER WAVE (+ fused classifier) ----------------
// lane = sub*16 + fl. Wave owns nodes nb0..nb0+3. One coalesced offs load (lanes 0-4)
// gives all boundaries; 4 independent srt hoists; gather loop interleaves the 4 nodes
// so 4 miss-chains overlap per lane. Butterfly reduce per node at the end.
// CLS=0: H[node] = relu(acc*dinv + bias). CLS=1: fused classifier -> part[blk][6].

#define AGG_GATHER(PRE, B, ACC)                                            \
  {                                                                        \
    int s_ = __shfl(PRE, (B) + sub, 64);                                   \
    ushort4 q_ = G2[(size_t)s_ * 16 + fl];                                 \
    ACC.x += bf16_to_f32(q_.x); ACC.y += bf16_to_f32(q_.y);                \
    ACC.z += bf16_to_f32(q_.z); ACC.w += bf16_to_f32(q_.w);                \
  }

template <int CLS>
__global__ __launch_bounds__(256) void aggregate(
    const ushort* __restrict__ Gb, const int* __restrict__ offs,
    const int* __restrict__ srt, const float* __restrict__ dinv,
    const float* __restrict__ bias, const float* __restrict__ Wc,
    float* __restrict__ H, float* __restrict__ part, int N) {
  int lane = threadIdx.x & 63, wv = threadIdx.x >> 6;
  int sub = lane >> 4, fl = lane & 15;
  int nb0 = (blockIdx.x * 4 + wv) * 4;  // first of this wave's 4 nodes
  const ushort4* G2 = (const ushort4*)Gb;

  // one coalesced load covers the 5 CSR boundaries of the wave's 4 nodes
  int o_l = 0;
  if (lane < 5) o_l = offs[min(nb0 + lane, N)];
  int e00 = __shfl(o_l, 0, 64), e01 = __shfl(o_l, 1, 64);
  int e02 = __shfl(o_l, 2, 64), e03 = __shfl(o_l, 3, 64);
  int e04 = __shfl(o_l, 4, 64);
  bool v0 = nb0 < N, v1 = nb0 + 1 < N, v2 = nb0 + 2 < N, v3 = nb0 + 3 < N;
  int d0 = v0 ? e01 - e00 : 0, d1 = v1 ? e02 - e01 : 0;
  int d2 = v2 ? e03 - e02 : 0, d3 = v3 ? e04 - e03 : 0;

  // 4 independent coalesced srt hoists (4 miss-chains start together)
  int pre0 = 0, pre1 = 0, pre2 = 0, pre3 = 0;
  if (d0 > 0) pre0 = srt[e00 + min(lane, d0 - 1)];
  if (d1 > 0) pre1 = srt[e01 + min(lane, d1 - 1)];
  if (d2 > 0) pre2 = srt[e02 + min(lane, d2 - 1)];
  if (d3 > 0) pre3 = srt[e03 + min(lane, d3 - 1)];

  float4 acc0 = make_float4(0.f, 0.f, 0.f, 0.f), acc1 = acc0, acc2 = acc0, acc3 = acc0;
  if (sub == 0) {  // self loops: 4 independent row reads
    if (v0) { ushort4 q = G2[(size_t)(nb0    ) * 16 + fl];
      acc0.x = bf16_to_f32(q.x); acc0.y = bf16_to_f32(q.y);
      acc0.z = bf16_to_f32(q.z); acc0.w = bf16_to_f32(q.w); }
    if (v1) { ushort4 q = G2[(size_t)(nb0 + 1) * 16 + fl];
      acc1.x = bf16_to_f32(q.x); acc1.y = bf16_to_f32(q.y);
      acc1.z = bf16_to_f32(q.z); acc1.w = bf16_to_f32(q.w); }
    if (v2) { ushort4 q = G2[(size_t)(nb0 + 2) * 16 + fl];
      acc2.x = bf16_to_f32(q.x); acc2.y = bf16_to_f32(q.y);
      acc2.z = bf16_to_f32(q.z); acc2.w = bf16_to_f32(q.w); }
    if (v3) { ushort4 q = G2[(size_t)(nb0 + 3) * 16 + fl];
      acc3.x = bf16_to_f32(q.x); acc3.y = bf16_to_f32(q.y);
      acc3.z = bf16_to_f32(q.z); acc3.w = bf16_to_f32(q.w); }
  }

  int dc0 = min(d0, 64), dc1 = min(d1, 64), dc2 = min(d2, 64), dc3 = min(d3, 64);
  int Rmax = max(max(dc0, dc1), max(dc2, dc3)) >> 2;
  for (int r = 0; r < Rmax; ++r) {     // interleaved: 4 independent gathers in flight/lane
    int b = r << 2;
    if (b + 4 <= dc0) AGG_GATHER(pre0, b, acc0);
    if (b + 4 <= dc1) AGG_GATHER(pre1, b, acc1);
    if (b + 4 <= dc2) AGG_GATHER(pre2, b, acc2);
    if (b + 4 <= dc3) AGG_GATHER(pre3, b, acc3);
  }
  // tails (rem 1..3); rem is wave-uniform so the shfl stays convergent
  { int t = dc0 & ~3, rem = dc0 - t;
    if (rem) { int s = __shfl(pre0, t + sub, 64);
      if (sub < rem) { ushort4 q = G2[(size_t)s * 16 + fl];
        acc0.x += bf16_to_f32(q.x); acc0.y += bf16_to_f32(q.y);
        acc0.z += bf16_to_f32(q.z); acc0.w += bf16_to_f32(q.w); } } }
  { int t = dc1 & ~3, rem = dc1 - t;
    if (rem) { int s = __shfl(pre1, t + sub, 64);
      if (sub < rem) { ushort4 q = G2[(size_t)s * 16 + fl];
        acc1.x += bf16_to_f32(q.x); acc1.y += bf16_to_f32(q.y);
        acc1.z += bf16_to_f32(q.z); acc1.w += bf16_to_f32(q.w); } } }
  { int t = dc2 & ~3, rem = dc2 - t;
    if (rem) { int s = __shfl(pre2, t + sub, 64);
      if (sub < rem) { ushort4 q = G2[(size_t)s * 16 + fl];
        acc2.x += bf16_to_f32(q.x); acc2.y += bf16_to_f32(q.y);
        acc2.z += bf16_to_f32(q.z); acc2.w += bf16_to_f32(q.w); } } }
  { int t = dc3 & ~3, rem = dc3 - t;
    if (rem) { int s = __shfl(pre3, t + sub, 64);
      if (sub < rem) { ushort4 q = G2[(size_t)s * 16 + fl];
        acc3.x += bf16_to_f32(q.x); acc3.y += bf16_to_f32(q.y);
        acc3.z += bf16_to_f32(q.z); acc3.w += bf16_to_f32(q.w); } } }

  // deg>64 spillover (rare: Poisson(16) -> ~never; correctness only)
  if (d0 > 64) { for (int e = e00 + 64; e < e01; ++e) { if (sub == 0) {
        int s = srt[e]; ushort4 q = G2[(size_t)s * 16 + fl];
        acc0.x += bf16_to_f32(q.x); acc0.y += bf16_to_f32(q.y);
        acc0.z += bf16_to_f32(q.z); acc0.w += bf16_to_f32(q.w); } } }
  if (d1 > 64) { for (int e = e01 + 64; e < e02; ++e) { if (sub == 0) {
        int s = srt[e]; ushort4 q = G2[(size_t)s * 16 + fl];
        acc1.x += bf16_to_f32(q.x); acc1.y += bf16_to_f32(q.y);
        acc1.z += bf16_to_f32(q.z); acc1.w += bf16_to_f32(q.w); } } }
  if (d2 > 64) { for (int e = e02 + 64; e < e03; ++e) { if (sub == 0) {
        int s = srt[e]; ushort4 q = G2[(size_t)s * 16 + fl];
        acc2.x += bf16_to_f32(q.x); acc2.y += bf16_to_f32(q.y);
        acc2.z += bf16_to_f32(q.z); acc2.w += bf16_to_f32(q.w); } } }
  if (d3 > 64) { for (int e = e03 + 64; e < e04; ++e) { if (sub == 0) {
        int s = srt[e]; ushort4 q = G2[(size_t)s * 16 + fl];
        acc3.x += bf16_to_f32(q.x); acc3.y += bf16_to_f32(q.y);
        acc3.z += bf16_to_f32(q.z); acc3.w += bf16_to_f32(q.w); } } }

  // butterfly reduce each node's acc across the 4 sub groups
#pragma unroll
  for (int m = 16; m < 64; m <<= 1) {
    acc0.x += __shfl_xor(acc0.x, m, 64); acc0.y += __shfl_xor(acc0.y, m, 64);
    acc0.z += __shfl_xor(acc0.z, m, 64); acc0.w += __shfl_xor(acc0.w, m, 64);
    acc1.x += __shfl_xor(acc1.x, m, 64); acc1.y += __shfl_xor(acc1.y, m, 64);
    acc1.z += __shfl_xor(acc1.z, m, 64); acc1.w += __shfl_xor(acc1.w, m, 64);
    acc2.x += __shfl_xor(acc2.x, m, 64); acc2.y += __shfl_xor(acc2.y, m, 64);
    acc2.z += __shfl_xor(acc2.z, m, 64); acc2.w += __shfl_xor(acc2.w, m, 64);
    acc3.x += __shfl_xor(acc3.x, m, 64); acc3.y += __shfl_xor(acc3.y, m, 64);
    acc3.z += __shfl_xor(acc3.z, m, 64); acc3.w += __shfl_xor(acc3.w, m, 64);
  }

  if (CLS == 0) {
    if (sub == 0) {
      float4 bb = ((const float4*)bias)[fl];
      if (v0) { float dn = dinv[nb0];
        float4 r; r.x = fmaxf(fmaf(acc0.x, dn, bb.x), 0.f);
        r.y = fmaxf(fmaf(acc0.y, dn, bb.y), 0.f);
        r.z = fmaxf(fmaf(acc0.z, dn, bb.z), 0.f);
        r.w = fmaxf(fmaf(acc0.w, dn, bb.w), 0.f);
        ((float4*)H)[(size_t)(nb0    ) * 16 + fl] = r; }
      if (v1) { float dn = dinv[nb0 + 1];
        float4 r; r.x = fmaxf(fmaf(acc1.x, dn, bb.x), 0.f);
        r.y = fmaxf(fmaf(acc1.y, dn, bb.y), 0.f);
        r.z = fmaxf(fmaf(acc1.z, dn, bb.z), 0.f);
        r.w = fmaxf(fmaf(acc1.w, dn, bb.w), 0.f);
        ((float4*)H)[(size_t)(nb0 + 1) * 16 + fl] = r; }
      if (v2) { float dn = dinv[nb0 + 2];
        float4 r; r.x = fmaxf(fmaf(acc2.x, dn, bb.x), 0.f);
        r.y = fmaxf(fmaf(acc2.y, dn, bb.y), 0.f);
        r.z = fmaxf(fmaf(acc2.z, dn, bb.z), 0.f);
        r.w = fmaxf(fmaf(acc2.w, dn, bb.w), 0.f);
        ((float4*)H)[(size_t)(nb0 + 2) * 16 + fl] = r; }
      if (v3) { float dn = dinv[nb0 + 3];
        float4 r; r.x = fmaxf(fmaf(acc3.x, dn, bb.x), 0.f);
        r.y = fmaxf(fmaf(acc3.y, dn, bb.y), 0.f);
        r.z = fmaxf(fmaf(acc3.z, dn, bb.z), 0.f);
        r.w = fmaxf(fmaf(acc3.w, dn, bb.w), 0.f);
        ((float4*)H)[(size_t)(nb0 + 3) * 16 + fl] = r; }
    }
  } else {
    float a[6] = {0.f, 0.f, 0.f, 0.f, 0.f, 0.f};
    if (sub == 0) {
      float4 bb = ((const float4*)bias)[fl];
#pragma unroll
      for (int i = 0; i < 4; ++i) {
        bool vi = (i == 0) ? v0 : (i == 1) ? v1 : (i == 2) ? v2 : v3;
        if (!vi) continue;
        float4 ac = (i == 0) ? acc0 : (i == 1) ? acc1 : (i == 2) ? acc2 : acc3;
        int node = nb0 + i;
        float dn = dinv[node];
        float4 r;
        r.x = fmaxf(fmaf(ac.x, dn, bb.x), 0.f);
        r.y = fmaxf(fmaf(ac.y, dn, bb.y), 0.f);
        r.z = fmaxf(fmaf(ac.z, dn, bb.z), 0.f);
        r.w = fmaxf(fmaf(ac.w, dn, bb.w), 0.f);
        // Wc slice for feats 4fl..4fl+3 of this node: 24 contiguous floats
        const float4* w4 = (const float4*)(Wc + (size_t)node * 384 + fl * 24);
        float4 w0 = w4[0], w1 = w4[1], w2 = w4[2], w3 = w4[3], w4_ = w4[4], w5 = w4[5];
        // layout: [f0c0..f0c5 f1c0..f1c5 f2c0..f2c5 f3c0..f3c5]
        a[0] += fmaf(r.x, w0.x, fmaf(r.y, w1.z, fmaf(r.z, w3.x, r.w * w4_.z)));
        a[1] += fmaf(r.x, w0.y, fmaf(r.y, w1.w, fmaf(r.z, w3.y, r.w * w4_.w)));
        a[2] += fmaf(r.x, w0.z, fmaf(r.y, w2.x, fmaf(r.z, w3.z, r.w * w5.x)));
        a[3] += fmaf(r.x, w0.w, fmaf(r.y, w2.y, fmaf(r.z, w3.w, r.w * w5.y)));
        a[4] += fmaf(r.x, w1.x, fmaf(r.y, w2.z, fmaf(r.z, w4_.x, r.w * w5.z)));
        a[5] += fmaf(r.x, w1.y, fmaf(r.y, w2.w, fmaf(r.z, w4_.y, r.w * w5.w)));
      }
    }
#pragma unroll
    for (int c = 0; c < 6; ++c) {
      for (int d = 32; d > 0; d >>= 1) a[c] += __shfl_down(a[c], d, 64);
    }
    __shared__ float sh[4][6];
    if (lane == 0) {
#pragma unroll
      for (int c = 0; c < 6; ++c) sh[wv][c] = a[c];
    }
    __syncthreads();
    if (threadIdx.x == 0) {
#pragma unroll
      for (int c = 0; c < 6; ++c)
        part[(size_t)blockIdx.x * 6 + c] = sh[0][c] + sh[1][c] + sh[2][c] + sh[3][c];
    }
  }
}

// single block: sum part[nb][6], add bias, softmax, write out[6]
__global__ __launch_bounds__(1024) void reduce_softmax(
    const float* __restrict__ part, int nb,
    const float* __restrict__ bc, float* __restrict__ out) {
  int tid = threadIdx.x, lane = tid & 63, wv = tid >> 6;
  float a[6] = {0.f, 0.f, 0.f, 0.f, 0.f, 0.f};
  for (int b = tid; b < nb; b += 1024) {
    const float* p = part + (size_t)b * 6;
#pragma unroll
    for (int c = 0; c < 6; ++c) a[c] += p[c];
  }
#pragma unroll
  for (int c = 0; c < 6; ++c) {
    for (int d = 32; d > 0; d >>= 1) a[c] += __shfl_down(a[c], d, 64);
  }
  __shared__ float sh[16][6];
  if (lane == 0) {
#pragma unroll
    for (int c = 0; c < 6; ++c) sh[wv][c] = a[c];
  }
  __syncthreads();
  if (tid == 0) {
    float l[6], m = -1e30f;
#pragma unroll
    for (int c = 0; c < 6; ++c) {
      float t = 0.f;
      for (int w = 0; w < 16; ++w) t += sh[w][c];
      l[c] = t + bc[c];
      m = fmaxf(m, l[c]);
    }
    float s = 0.f;
#pragma unroll
    for (int c = 0; c < 6; ++c) { l[c] = __expf(l[c] - m); s += l[c]; }
    float inv = 1.f / s;
#pragma unroll
    for (int c = 0; c < 6; ++c) out[c] = l[c] * inv;
  }
}

// ---------------- launch ----------------

static inline size_t align4up(size_t x) { return (x + 3) & ~(size_t)3; }  // 4-elem = 16B

extern "C" void kernel_launch(void* const* d_in, const int* in_sizes, int n_in,
                              void* d_out, int out_size, void* d_ws, size_t ws_size,
                              hipStream_t stream) {
  const float* x  = (const float*)d_in[0];
  const int*   ei = (const int*)d_in[1];
  const float* W1 = (const float*)d_in[2];
  const float* b1 = (const float*)d_in[3];
  const float* W2 = (const float*)d_in[4];
  const float* b2 = (const float*)d_in[5];
  const float* Wc = (const float*)d_in[6];
  const float* bc = (const float*)d_in[7];
  float* out = (float*)d_out;

  const int N = in_sizes[0] / 128;  // 50000
  const int E = in_sizes[1] / 2;    // 800000
  const int* esrc = ei;
  const int* edst = ei + E;
  const int NR = (N + 1023) >> RBITS;  // 49 ranges (<= NR_MAX)
  const int AGRID = (N + 15) / 16;     // 3125 blocks, 16 nodes/block (4/wave)

  // 16B-aligned workspace carve
  size_t o = 0;
  int* offs   = (int*)d_ws + o;           o = align4up(o + N + 1);
  int* srt    = (int*)d_ws + o;           o = align4up(o + E);
  float* dinv = (float*)d_ws + o;         o = align4up(o + N);
  int* ghist  = (int*)d_ws + o;           o = align4up(o + (size_t)NR * NCH);
  ushort* Gb  = (ushort*)((int*)d_ws + o); o = align4up(o + (size_t)N * 32);  // N*64 bf16
  float* bufB = (float*)d_ws + o;         o = align4up(o + (size_t)N * 64);
  float* part = (float*)d_ws + o;         o = align4up(o + (size_t)AGRID * 6);
  int2* ebuf  = (int2*)bufB;  // aliases bufB: dead after csr_range, bufB written by agg1

  hist_ranges<<<NCH, 256, 0, stream>>>(edst, ghist, NR, E);
  scatter_ranges<<<NCH, 256, 0, stream>>>(esrc, edst, ghist, ebuf, NR, E);
  csr_range<<<NR, 1024, 0, stream>>>(ebuf, ghist, offs, srt, dinv, N, E, NR);

  gemm_scale<128, 32><<<(N + 31) / 32, 256, 0, stream>>>(x, W1, dinv, Gb, N);
  aggregate<0><<<AGRID, 256, 0, stream>>>(Gb, offs, srt, dinv, b1, nullptr, bufB, nullptr, N);
  gemm_scale<64, 32><<<(N + 31) / 32, 256, 0, stream>>>(bufB, W2, dinv, Gb, N);
  aggregate<1><<<AGRID, 256, 0, stream>>>(Gb, offs, srt, dinv, b2, Wc, nullptr, part, N);

  reduce_softmax<<<1, 1024, 0, stream>>>(part, AGRID, bc, out);
}

// Round 14
// 159.728 us; speedup vs baseline: 1.3990x; 1.0337x over previous
//
#include <hip/hip_runtime.h>
#include <math.h>

// SensorGNN: 2-layer GCN (N=50000, E=800000, F=128, H=64) + flat classifier (6 classes).
// Graph build = counting sort by dst-range: hist_ranges -> scatter_ranges(folded scan) ->
//   csr_range(folded prefix; dinv/offs/srt).
// Compute: gemm1(+dinv->bf16 Gb1) -> agg1(fused h@W2 -> bf16 Gb2) -> agg2(fused classifier)
//   -> reduce+softmax.  7 launches, H never materialized.
// r3: same-line global atomics serialize cross-XCD. r4/5: random atomic scatter bounces
// lines via HBM. r6: edge replication = occupancy loss. r7/8/9/10/12/13: SIX aggregate
// structures (ILP, bytes, residency, 2-phase, multi-node) all land 45-57us ->
// ~47us/aggregate is the floor for this scatter-gather; 1-node/wave (r11) is best.
// r11 lesson: latency-bound aggregate absorbs streaming+VALU epilogues for free
// (classifier fusion) -> r14 fuses gemm2 the same way and deletes the H roundtrip.

#define NCH 256          // edge chunk blocks
#define RBITS 10         // range = 1024 nodes
#define NR_MAX 64

__device__ __forceinline__ ushort f32_to_bf16(float f) {  // RTN-even
  unsigned u = __float_as_uint(f);
  return (ushort)((u + 0x7fffu + ((u >> 16) & 1u)) >> 16);
}
__device__ __forceinline__ float bf16_to_f32(ushort h) {
  return __uint_as_float(((unsigned)h) << 16);
}

// ---------------- pass A: per-chunk range histograms (raw counts) ----------------

__global__ __launch_bounds__(256) void hist_ranges(
    const int* __restrict__ dst, int* __restrict__ ghist, int NR, int E) {
  __shared__ int h[NR_MAX];
  int tid = threadIdx.x, c = blockIdx.x;
  if (tid < NR) h[tid] = 0;
  __syncthreads();
  int E4 = E >> 2;
  int CH4 = (E4 + NCH - 1) / NCH;
  int i0 = c * CH4, i1 = min(i0 + CH4, E4);
  const int4* d4 = (const int4*)dst;
  for (int i = i0 + tid; i < i1; i += 256) {
    int4 d = d4[i];
    atomicAdd(&h[d.x >> RBITS], 1);
    atomicAdd(&h[d.y >> RBITS], 1);
    atomicAdd(&h[d.z >> RBITS], 1);
    atomicAdd(&h[d.w >> RBITS], 1);
  }
  if (c == NCH - 1) {
    for (int e = (E4 << 2) + tid; e < E; e += 256) atomicAdd(&h[dst[e] >> RBITS], 1);
  }
  __syncthreads();
  if (tid < NR) ghist[tid * NCH + c] = h[tid];  // range-major, chunk-minor (raw counts)
}

// ---------------- pass B: scatter with per-block folded prefix scan ----------------

__global__ __launch_bounds__(256) void scatter_ranges(
    const int* __restrict__ src, const int* __restrict__ dst,
    const int* __restrict__ ghist, int2* __restrict__ ebuf, int NR, int E) {
  __shared__ int cur[NR_MAX];
  __shared__ int rowpre[NR_MAX + 1];
  int tid = threadIdx.x, c = blockIdx.x;
  if (tid < NR) {  // row totals (vectorized over 50KB L2-hot hist)
    const int4* row = (const int4*)(ghist + tid * NCH);
    int s = 0;
    for (int q = 0; q < NCH / 4; ++q) { int4 v = row[q]; s += v.x + v.y + v.z + v.w; }
    rowpre[tid + 1] = s;
  }
  __syncthreads();
  if (tid == 0) {
    rowpre[0] = 0;
    for (int i = 1; i <= NR; ++i) rowpre[i] += rowpre[i - 1];
  }
  __syncthreads();
  if (tid < NR) {  // + chunks < c within own row
    int s = rowpre[tid];
    const int* row = ghist + tid * NCH;
    const int4* row4 = (const int4*)row;
    int c4 = c >> 2;
    for (int q = 0; q < c4; ++q) { int4 v = row4[q]; s += v.x + v.y + v.z + v.w; }
    for (int cc = c4 << 2; cc < c; ++cc) s += row[cc];
    cur[tid] = s;
  }
  __syncthreads();
  int E4 = E >> 2;
  int CH4 = (E4 + NCH - 1) / NCH;
  int i0 = c * CH4, i1 = min(i0 + CH4, E4);
  const int4* d4 = (const int4*)dst;
  const int4* s4 = (const int4*)src;
  for (int i = i0 + tid; i < i1; i += 256) {
    int4 d = d4[i];
    int4 s = s4[i];
    ebuf[atomicAdd(&cur[d.x >> RBITS], 1)] = make_int2(s.x, d.x);
    ebuf[atomicAdd(&cur[d.y >> RBITS], 1)] = make_int2(s.y, d.y);
    ebuf[atomicAdd(&cur[d.z >> RBITS], 1)] = make_int2(s.z, d.z);
    ebuf[atomicAdd(&cur[d.w >> RBITS], 1)] = make_int2(s.w, d.w);
  }
  if (c == NCH - 1) {
    for (int e = (E4 << 2) + tid; e < E; e += 256)
      ebuf[atomicAdd(&cur[dst[e] >> RBITS], 1)] = make_int2(src[e], dst[e]);
  }
}

// ---------------- pass C: per-range CSR build (dinv, offs, srt) ----------------

__global__ __launch_bounds__(1024) void csr_range(
    const int2* __restrict__ ebuf, const int* __restrict__ ghist,
    int* __restrict__ offs, int* __restrict__ srt, float* __restrict__ dinv,
    int N, int E, int NR) {
  __shared__ int hist[1024];
  __shared__ int wtot[16];
  __shared__ int rowpre[NR_MAX + 1];
  int r = blockIdx.x;
  int lo = r << RBITS;
  int len = min(1024, N - lo);
  int tid = threadIdx.x, lane = tid & 63, wv = tid >> 6;
  if (tid < NR) {
    const int4* row = (const int4*)(ghist + tid * NCH);
    int s = 0;
    for (int q = 0; q < NCH / 4; ++q) { int4 v = row[q]; s += v.x + v.y + v.z + v.w; }
    rowpre[tid + 1] = s;
  }
  if (tid < len) hist[tid] = 0;
  __syncthreads();
  if (tid == 0) {
    rowpre[0] = 0;
    for (int i = 1; i <= NR; ++i) rowpre[i] += rowpre[i - 1];
  }
  __syncthreads();
  int S = rowpre[r], S1 = rowpre[r + 1];
  for (int i = S + tid; i < S1; i += 1024) atomicAdd(&hist[ebuf[i].y - lo], 1);
  __syncthreads();
  int v = (tid < len) ? hist[tid] : 0;
  if (tid < len) dinv[lo + tid] = rsqrtf((float)(v + 1));  // +1 self loop
  // exclusive scan of v across 1024 threads
  int x = v;
#pragma unroll
  for (int d = 1; d < 64; d <<= 1) { int y = __shfl_up(x, d, 64); if (lane >= d) x += y; }
  if (lane == 63) wtot[wv] = x;
  __syncthreads();
  if (wv == 0 && lane < 16) {
    int t = wtot[lane], xx = t;
#pragma unroll
    for (int d = 1; d < 16; d <<= 1) { int y = __shfl_up(xx, d, 64); if (lane >= d) xx += y; }
    wtot[lane] = xx - t;
  }
  __syncthreads();
  int excl = x - v + wtot[wv];
  if (tid < len) {
    offs[lo + tid] = S + excl;
    hist[tid] = S + excl;  // reuse as cursor
  }
  if (r == 0 && tid == 0) offs[N] = E;
  __syncthreads();
  for (int i = S + tid; i < S1; i += 1024) {
    int2 e = ebuf[i];
    srt[atomicAdd(&hist[e.y - lo], 1)] = e.x;
  }
}

// ---------------- dense transform: Gb = bf16((X @ W) * dinv[row]) ----------------
// Unroll capped at 4 to avoid the round-1 VGPR blowup (256 VGPR + 380MB scratch spill).

template <int K, int ROWS>
__global__ __launch_bounds__(256) void gemm_scale(
    const float* __restrict__ X, const float* __restrict__ W,
    const float* __restrict__ dinv, ushort* __restrict__ Gb, int N) {
  __shared__ float smw[K * 64];
  __shared__ float xs[ROWS * K];
  int tid = threadIdx.x, lane = tid & 63, wv = tid >> 6;
  for (int idx = tid; idx < K * 16; idx += 256)
    ((float4*)smw)[idx] = ((const float4*)W)[idx];
  int row0 = blockIdx.x * ROWS;
  int base = row0 * K;
  int cnt4 = (min(ROWS * K, N * K - base)) >> 2;  // K%4==0 so exact
  const float4* X4 = (const float4*)(X + base);
  for (int idx = tid; idx < cnt4; idx += 256) ((float4*)xs)[idx] = X4[idx];
  __syncthreads();

  constexpr int RW = ROWS / 4;  // rows per wave
  float acc[RW];
#pragma unroll
  for (int r = 0; r < RW; ++r) acc[r] = 0.f;
  const float* xr = &xs[(wv * RW) * K];
#pragma unroll 4
  for (int k = 0; k < K; ++k) {
    float wval = smw[k * 64 + lane];  // lane-contiguous: 2-way bank alias = free
#pragma unroll
    for (int r = 0; r < RW; ++r) acc[r] = fmaf(xr[r * K + k], wval, acc[r]);  // LDS broadcast
  }
#pragma unroll
  for (int r = 0; r < RW; ++r) {
    int row = row0 + wv * RW + r;
    if (row < N) Gb[(size_t)row * 64 + lane] = f32_to_bf16(acc[r] * dinv[row]);
  }
}

// ---------------- aggregation with fused dense epilogue ----------------
// one wave per node (r11 structure: proven-best 47.4us); lane = sub*16 + fl;
// indices hoisted to regs + dynamic shfl; 8 bf16 rows (2 lines) in flight.
// After the butterfly reduce ALL lanes hold the full aggregated row (quad fl).
// MODE 0 (layer 1): h = relu(acc*dinv + b1); fused h@W2: sub s computes k in
//   [16s,16s+16) partial of output quad 4fl..4fl+3 (16 shfl + 16 L1-hit W2 float4
//   + 64 FMA), 2-step butterfly combines, Gout[node] = bf16(out * dinv). gemm2 GONE.
// MODE 1 (layer 2): h = relu(acc*dinv + b2); fused classifier dot with node's Wc
//   slice -> part[blk][6] (h never stored).

template <int MODE>
__global__ __launch_bounds__(256) void aggregate(
    const ushort* __restrict__ Gb, const int* __restrict__ offs,
    const int* __restrict__ srt, const float* __restrict__ dinv,
    const float* __restrict__ bias, const float* __restrict__ Wx,  // W2 (MODE0) / Wc (MODE1)
    ushort* __restrict__ Gout, float* __restrict__ part, int N) {
  int lane = threadIdx.x & 63, wv = threadIdx.x >> 6;
  int sub = lane >> 4, fl = lane & 15;
  int node = blockIdx.x * 4 + wv;
  const ushort4* G2 = (const ushort4*)Gb;  // 16 x ushort4 per 64-feat row

  if (MODE == 0 && node >= N) return;  // MODE1 block-reduce needs all threads

  int e0 = 0, e1 = 0;
  if (node < N) { e0 = offs[node]; e1 = offs[node + 1]; }
  int deg = e1 - e0;

  float4 accA = make_float4(0.f, 0.f, 0.f, 0.f);
  float4 accB = make_float4(0.f, 0.f, 0.f, 0.f);
  if (sub == 0 && node < N) {  // self loop
    ushort4 q = G2[(size_t)node * 16 + fl];
    accA.x = bf16_to_f32(q.x); accA.y = bf16_to_f32(q.y);
    accA.z = bf16_to_f32(q.z); accA.w = bf16_to_f32(q.w);
  }

  // hoist up to 64 edge indices into registers (coalesced; mean deg 16)
  int pre = (deg > 0) ? srt[e0 + min(lane, deg - 1)] : 0;

  int dcap = min(deg, 64);
  int base = 0;
  for (; base + 7 < dcap; base += 8) {   // 8 rows in flight, no index-load chain
    int sA = __shfl(pre, base + sub, 64);
    int sB = __shfl(pre, base + 4 + sub, 64);
    ushort4 qA = G2[(size_t)sA * 16 + fl];
    ushort4 qB = G2[(size_t)sB * 16 + fl];
    accA.x += bf16_to_f32(qA.x); accA.y += bf16_to_f32(qA.y);
    accA.z += bf16_to_f32(qA.z); accA.w += bf16_to_f32(qA.w);
    accB.x += bf16_to_f32(qB.x); accB.y += bf16_to_f32(qB.y);
    accB.z += bf16_to_f32(qB.z); accB.w += bf16_to_f32(qB.w);
  }
  for (; base + 3 < dcap; base += 4) {
    int s = __shfl(pre, base + sub, 64);
    ushort4 q = G2[(size_t)s * 16 + fl];
    accA.x += bf16_to_f32(q.x); accA.y += bf16_to_f32(q.y);
    accA.z += bf16_to_f32(q.z); accA.w += bf16_to_f32(q.w);
  }
  int e = e0 + base;
  for (; e + 3 < e1; e += 4) {           // deg>64 spillover (rare)
    int s = srt[e + sub];
    ushort4 q = G2[(size_t)s * 16 + fl];
    accA.x += bf16_to_f32(q.x); accA.y += bf16_to_f32(q.y);
    accA.z += bf16_to_f32(q.z); accA.w += bf16_to_f32(q.w);
  }
  int rem = e1 - e;                      // 0..3 remainder
  if (sub < rem) {
    int s = srt[e + sub];
    ushort4 q = G2[(size_t)s * 16 + fl];
    accA.x += bf16_to_f32(q.x); accA.y += bf16_to_f32(q.y);
    accA.z += bf16_to_f32(q.z); accA.w += bf16_to_f32(q.w);
  }

  float4 acc;
  acc.x = accA.x + accB.x; acc.y = accA.y + accB.y;
  acc.z = accA.z + accB.z; acc.w = accA.w + accB.w;
#pragma unroll
  for (int m = 16; m < 64; m <<= 1) {
    acc.x += __shfl_xor(acc.x, m, 64);
    acc.y += __shfl_xor(acc.y, m, 64);
    acc.z += __shfl_xor(acc.z, m, 64);
    acc.w += __shfl_xor(acc.w, m, 64);
  }

  if (MODE == 0) {
    // ---- fused gemm2 epilogue: Gout[node] = bf16( relu(acc*dinv+b1) @ W2 * dinv ) ----
    if (node < N) {
      float dn = dinv[node];
      float4 bb = ((const float4*)bias)[fl];
      float4 r;
      r.x = fmaxf(fmaf(acc.x, dn, bb.x), 0.f);
      r.y = fmaxf(fmaf(acc.y, dn, bb.y), 0.f);
      r.z = fmaxf(fmaf(acc.z, dn, bb.z), 0.f);
      r.w = fmaxf(fmaf(acc.w, dn, bb.w), 0.f);
      // sub s handles k in [16s,16s+16): quads g=4s+t held by lane (s, g)
      float4 o = make_float4(0.f, 0.f, 0.f, 0.f);
#pragma unroll
      for (int t = 0; t < 4; ++t) {
        int g = 4 * sub + t;
        int srcl = (lane & 48) | g;     // same sub, lane fl=g holds h quad g
        float h0 = __shfl(r.x, srcl, 64);
        float h1 = __shfl(r.y, srcl, 64);
        float h2 = __shfl(r.z, srcl, 64);
        float h3 = __shfl(r.w, srcl, 64);
        const float* wp = Wx + (size_t)(4 * g) * 64 + 4 * fl;  // W2[k][j], L1-resident 16KB
        float4 w0 = *(const float4*)(wp);
        float4 w1 = *(const float4*)(wp + 64);
        float4 w2 = *(const float4*)(wp + 128);
        float4 w3 = *(const float4*)(wp + 192);
        o.x = fmaf(h0, w0.x, fmaf(h1, w1.x, fmaf(h2, w2.x, fmaf(h3, w3.x, o.x))));
        o.y = fmaf(h0, w0.y, fmaf(h1, w1.y, fmaf(h2, w2.y, fmaf(h3, w3.y, o.y))));
        o.z = fmaf(h0, w0.z, fmaf(h1, w1.z, fmaf(h2, w2.z, fmaf(h3, w3.z, o.z))));
        o.w = fmaf(h0, w0.w, fmaf(h1, w1.w, fmaf(h2, w2.w, fmaf(h3, w3.w, o.w))));
      }
#pragma unroll
      for (int m = 16; m < 64; m <<= 1) {  // combine the 4 k-partitions
        o.x += __shfl_xor(o.x, m, 64);
        o.y += __shfl_xor(o.y, m, 64);
        o.z += __shfl_xor(o.z, m, 64);
        o.w += __shfl_xor(o.w, m, 64);
      }
      if (sub == 0) {
        ushort4 q;
        q.x = f32_to_bf16(o.x * dn);
        q.y = f32_to_bf16(o.y * dn);
        q.z = f32_to_bf16(o.z * dn);
        q.w = f32_to_bf16(o.w * dn);
        ((ushort4*)Gout)[(size_t)node * 16 + fl] = q;
      }
    }
  } else {
    // ---- fused classifier epilogue (r11, verified) ----
    float a[6] = {0.f, 0.f, 0.f, 0.f, 0.f, 0.f};
    if (sub == 0 && node < N) {
      float dn = dinv[node];
      float4 bb = ((const float4*)bias)[fl];
      float4 r;
      r.x = fmaxf(fmaf(acc.x, dn, bb.x), 0.f);
      r.y = fmaxf(fmaf(acc.y, dn, bb.y), 0.f);
      r.z = fmaxf(fmaf(acc.z, dn, bb.z), 0.f);
      r.w = fmaxf(fmaf(acc.w, dn, bb.w), 0.f);
      // Wc slice for feats 4fl..4fl+3 of this node: 24 contiguous floats
      const float4* w4 = (const float4*)(Wx + (size_t)node * 384 + fl * 24);
      float4 w0 = w4[0], w1 = w4[1], w2 = w4[2], w3 = w4[3], w4_ = w4[4], w5 = w4[5];
      // layout: [f0c0..f0c5 f1c0..f1c5 f2c0..f2c5 f3c0..f3c5]
      a[0] = fmaf(r.x, w0.x, fmaf(r.y, w1.z, fmaf(r.z, w3.x, r.w * w4_.z)));
      a[1] = fmaf(r.x, w0.y, fmaf(r.y, w1.w, fmaf(r.z, w3.y, r.w * w4_.w)));
      a[2] = fmaf(r.x, w0.z, fmaf(r.y, w2.x, fmaf(r.z, w3.z, r.w * w5.x)));
      a[3] = fmaf(r.x, w0.w, fmaf(r.y, w2.y, fmaf(r.z, w3.w, r.w * w5.y)));
      a[4] = fmaf(r.x, w1.x, fmaf(r.y, w2.z, fmaf(r.z, w4_.x, r.w * w5.z)));
      a[5] = fmaf(r.x, w1.y, fmaf(r.y, w2.w, fmaf(r.z, w4_.y, r.w * w5.w)));
    }
#pragma unroll
    for (int c = 0; c < 6; ++c) {
      for (int d = 32; d > 0; d >>= 1) a[c] += __shfl_down(a[c], d, 64);
    }
    __shared__ float sh[4][6];
    if (lane == 0) {
#pragma unroll
      for (int c = 0; c < 6; ++c) sh[wv][c] = a[c];
    }
    __syncthreads();
    if (threadIdx.x == 0) {
#pragma unroll
      for (int c = 0; c < 6; ++c)
        part[(size_t)blockIdx.x * 6 + c] = sh[0][c] + sh[1][c] + sh[2][c] + sh[3][c];
    }
  }
}

// single block: sum part[nb][6], add bias, softmax, write out[6]
__global__ __launch_bounds__(1024) void reduce_softmax(
    const float* __restrict__ part, int nb,
    const float* __restrict__ bc, float* __restrict__ out) {
  int tid = threadIdx.x, lane = tid & 63, wv = tid >> 6;
  float a[6] = {0.f, 0.f, 0.f, 0.f, 0.f, 0.f};
  for (int b = tid; b < nb; b += 1024) {
    const float* p = part + (size_t)b * 6;
#pragma unroll
    for (int c = 0; c < 6; ++c) a[c] += p[c];
  }
#pragma unroll
  for (int c = 0; c < 6; ++c) {
    for (int d = 32; d > 0; d >>= 1) a[c] += __shfl_down(a[c], d, 64);
  }
  __shared__ float sh[16][6];
  if (lane == 0) {
#pragma unroll
    for (int c = 0; c < 6; ++c) sh[wv][c] = a[c];
  }
  __syncthreads();
  if (tid == 0) {
    float l[6], m = -1e30f;
#pragma unroll
    for (int c = 0; c < 6; ++c) {
      float t = 0.f;
      for (int w = 0; w < 16; ++w) t += sh[w][c];
      l[c] = t + bc[c];
      m = fmaxf(m, l[c]);
    }
    float s = 0.f;
#pragma unroll
    for (int c = 0; c < 6; ++c) { l[c] = __expf(l[c] - m); s += l[c]; }
    float inv = 1.f / s;
#pragma unroll
    for (int c = 0; c < 6; ++c) out[c] = l[c] * inv;
  }
}

// ---------------- launch ----------------

static inline size_t align4up(size_t x) { return (x + 3) & ~(size_t)3; }  // 4-elem = 16B

extern "C" void kernel_launch(void* const* d_in, const int* in_sizes, int n_in,
                              void* d_out, int out_size, void* d_ws, size_t ws_size,
                              hipStream_t stream) {
  const float* x  = (const float*)d_in[0];
  const int*   ei = (const int*)d_in[1];
  const float* W1 = (const float*)d_in[2];
  const float* b1 = (const float*)d_in[3];
  const float* W2 = (const float*)d_in[4];
  const float* b2 = (const float*)d_in[5];
  const float* Wc = (const float*)d_in[6];
  const float* bc = (const float*)d_in[7];
  float* out = (float*)d_out;

  const int N = in_sizes[0] / 128;  // 50000
  const int E = in_sizes[1] / 2;    // 800000
  const int* esrc = ei;
  const int* edst = ei + E;
  const int NR = (N + 1023) >> RBITS;  // 49 ranges (<= NR_MAX)
  const int AGRID = (N + 3) / 4;       // 12500 aggregate blocks (1 node/wave)

  // 16B-aligned workspace carve
  size_t o = 0;
  int* offs   = (int*)d_ws + o;            o = align4up(o + N + 1);
  int* srt    = (int*)d_ws + o;            o = align4up(o + E);
  float* dinv = (float*)d_ws + o;          o = align4up(o + N);
  int* ghist  = (int*)d_ws + o;            o = align4up(o + (size_t)NR * NCH);
  ushort* Gb1 = (ushort*)((int*)d_ws + o); o = align4up(o + (size_t)N * 32);  // N*64 bf16
  ushort* Gb2 = (ushort*)((int*)d_ws + o); o = align4up(o + max((size_t)N * 32, (size_t)E * 2));
  float* part = (float*)d_ws + o;          o = align4up(o + (size_t)AGRID * 6);
  int2* ebuf  = (int2*)Gb2;  // aliases Gb2: ebuf dead after csr_range, Gb2 written by agg1

  hist_ranges<<<NCH, 256, 0, stream>>>(edst, ghist, NR, E);
  scatter_ranges<<<NCH, 256, 0, stream>>>(esrc, edst, ghist, ebuf, NR, E);
  csr_range<<<NR, 1024, 0, stream>>>(ebuf, ghist, offs, srt, dinv, N, E, NR);

  gemm_scale<128, 32><<<(N + 31) / 32, 256, 0, stream>>>(x, W1, dinv, Gb1, N);
  aggregate<0><<<AGRID, 256, 0, stream>>>(Gb1, offs, srt, dinv, b1, W2, Gb2, nullptr, N);
  aggregate<1><<<AGRID, 256, 0, stream>>>(Gb2, offs, srt, dinv, b2, Wc, nullptr, part, N);

  reduce_softmax<<<1, 1024, 0, stream>>>(part, AGRID, bc, out);
}

// Round 15
// 157.711 us; speedup vs baseline: 1.4169x; 1.0128x over previous
//
#include <hip/hip_runtime.h>
#include <math.h>

// SensorGNN: 2-layer GCN (N=50000, E=800000, F=128, H=64) + flat classifier (6 classes).
// Graph build = counting sort by dst-range (RBITS=8: 256-node ranges, NR=196):
//   hist_ranges -> scatter_ranges(folded scan, PACKED src|dstlo ebuf) ->
//   csr_range(folded prefix; dinv/offs/ushort srt).
// Compute: gemm1(+dinv->bf16 Gb1) -> agg1(fused h@W2 -> bf16 Gb2) -> agg2(fused classifier)
//   -> reduce+softmax.  7 launches, H never materialized.
// r3: same-line global atomics serialize cross-XCD. r4/5: random atomic scatter bounces
// lines via HBM. r6: edge replication = occupancy loss. r7-r13: SIX aggregate structures
// (ILP, bytes, residency, 2-phase, multi-node) all land 45-57us -> ~47us/aggregate is the
// random-gather service floor; 1-node/wave (r11) is best. r11/r14: latency-bound aggregate
// absorbs dense epilogues for free (classifier + gemm2 fused, H deleted).
// r15: graph build was 49-block (19% CU) + fat int2 ebuf -> RBITS=8 (196 blocks),
//   packed int ebuf (src 16b | dstlo 8b), ushort srt.

#define NCH 256          // edge chunk blocks
#define RBITS 8          // range = 256 nodes
#define NR_MAX 256

__device__ __forceinline__ ushort f32_to_bf16(float f) {  // RTN-even
  unsigned u = __float_as_uint(f);
  return (ushort)((u + 0x7fffu + ((u >> 16) & 1u)) >> 16);
}
__device__ __forceinline__ float bf16_to_f32(ushort h) {
  return __uint_as_float(((unsigned)h) << 16);
}

// ---------------- pass A: per-chunk range histograms (raw counts) ----------------

__global__ __launch_bounds__(256) void hist_ranges(
    const int* __restrict__ dst, int* __restrict__ ghist, int NR, int E) {
  __shared__ int h[NR_MAX];
  int tid = threadIdx.x, c = blockIdx.x;
  for (int i = tid; i < NR; i += 256) h[i] = 0;
  __syncthreads();
  int E4 = E >> 2;
  int CH4 = (E4 + NCH - 1) / NCH;
  int i0 = c * CH4, i1 = min(i0 + CH4, E4);
  const int4* d4 = (const int4*)dst;
  for (int i = i0 + tid; i < i1; i += 256) {
    int4 d = d4[i];
    atomicAdd(&h[d.x >> RBITS], 1);
    atomicAdd(&h[d.y >> RBITS], 1);
    atomicAdd(&h[d.z >> RBITS], 1);
    atomicAdd(&h[d.w >> RBITS], 1);
  }
  if (c == NCH - 1) {
    for (int e = (E4 << 2) + tid; e < E; e += 256) atomicAdd(&h[dst[e] >> RBITS], 1);
  }
  __syncthreads();
  for (int i = tid; i < NR; i += 256) ghist[i * NCH + c] = h[i];  // range-major, chunk-minor
}

// ---------------- pass B: scatter with per-block folded prefix scan ----------------
// ebuf entry = src | ((dst & 255) << 16)  (src < 2^16, dst-lo 8 bits; 24 bits total)

__global__ __launch_bounds__(256) void scatter_ranges(
    const int* __restrict__ src, const int* __restrict__ dst,
    const int* __restrict__ ghist, int* __restrict__ ebuf, int NR, int E) {
  __shared__ int cur[NR_MAX];
  __shared__ int rowpre[NR_MAX + 1];
  int tid = threadIdx.x, c = blockIdx.x;
  if (tid < NR) {  // row totals (vectorized over 200KB L2-hot hist)
    const int4* row = (const int4*)(ghist + tid * NCH);
    int s = 0;
    for (int q = 0; q < NCH / 4; ++q) { int4 v = row[q]; s += v.x + v.y + v.z + v.w; }
    rowpre[tid + 1] = s;
  }
  __syncthreads();
  if (tid == 0) {
    rowpre[0] = 0;
    for (int i = 1; i <= NR; ++i) rowpre[i] += rowpre[i - 1];
  }
  __syncthreads();
  if (tid < NR) {  // + chunks < c within own row
    int s = rowpre[tid];
    const int* row = ghist + tid * NCH;
    const int4* row4 = (const int4*)row;
    int c4 = c >> 2;
    for (int q = 0; q < c4; ++q) { int4 v = row4[q]; s += v.x + v.y + v.z + v.w; }
    for (int cc = c4 << 2; cc < c; ++cc) s += row[cc];
    cur[tid] = s;
  }
  __syncthreads();
  int E4 = E >> 2;
  int CH4 = (E4 + NCH - 1) / NCH;
  int i0 = c * CH4, i1 = min(i0 + CH4, E4);
  const int4* d4 = (const int4*)dst;
  const int4* s4 = (const int4*)src;
  for (int i = i0 + tid; i < i1; i += 256) {
    int4 d = d4[i];
    int4 s = s4[i];
    ebuf[atomicAdd(&cur[d.x >> RBITS], 1)] = s.x | ((d.x & 255) << 16);
    ebuf[atomicAdd(&cur[d.y >> RBITS], 1)] = s.y | ((d.y & 255) << 16);
    ebuf[atomicAdd(&cur[d.z >> RBITS], 1)] = s.z | ((d.z & 255) << 16);
    ebuf[atomicAdd(&cur[d.w >> RBITS], 1)] = s.w | ((d.w & 255) << 16);
  }
  if (c == NCH - 1) {
    for (int e = (E4 << 2) + tid; e < E; e += 256)
      ebuf[atomicAdd(&cur[dst[e] >> RBITS], 1)] = src[e] | ((dst[e] & 255) << 16);
  }
}

// ---------------- pass C: per-range CSR build (dinv, offs, ushort srt) ----------------

__global__ __launch_bounds__(1024) void csr_range(
    const int* __restrict__ ebuf, const int* __restrict__ ghist,
    int* __restrict__ offs, ushort* __restrict__ srt, float* __restrict__ dinv,
    int N, int E, int NR) {
  __shared__ int hist[NR_MAX];   // 256 per-node counts -> cursors
  __shared__ int wtot[16];
  __shared__ int rowpre[NR_MAX + 1];
  int r = blockIdx.x;
  int lo = r << RBITS;
  int len = min(1 << RBITS, N - lo);
  int tid = threadIdx.x, lane = tid & 63, wv = tid >> 6;
  if (tid < NR) {
    const int4* row = (const int4*)(ghist + tid * NCH);
    int s = 0;
    for (int q = 0; q < NCH / 4; ++q) { int4 v = row[q]; s += v.x + v.y + v.z + v.w; }
    rowpre[tid + 1] = s;
  }
  if (tid < len) hist[tid] = 0;
  __syncthreads();
  if (tid == 0) {
    rowpre[0] = 0;
    for (int i = 1; i <= NR; ++i) rowpre[i] += rowpre[i - 1];
  }
  __syncthreads();
  int S = rowpre[r], S1 = rowpre[r + 1];
  for (int i = S + tid; i < S1; i += 1024) atomicAdd(&hist[ebuf[i] >> 16], 1);
  __syncthreads();
  int v = (tid < len) ? hist[tid] : 0;
  if (tid < len) dinv[lo + tid] = rsqrtf((float)(v + 1));  // +1 self loop
  // exclusive scan of v across 1024 threads (only first len nonzero)
  int x = v;
#pragma unroll
  for (int d = 1; d < 64; d <<= 1) { int y = __shfl_up(x, d, 64); if (lane >= d) x += y; }
  if (lane == 63) wtot[wv] = x;
  __syncthreads();
  if (wv == 0 && lane < 16) {
    int t = wtot[lane], xx = t;
#pragma unroll
    for (int d = 1; d < 16; d <<= 1) { int y = __shfl_up(xx, d, 64); if (lane >= d) xx += y; }
    wtot[lane] = xx - t;
  }
  __syncthreads();
  int excl = x - v + wtot[wv];
  if (tid < len) {
    offs[lo + tid] = S + excl;
    hist[tid] = S + excl;  // reuse as cursor
  }
  if (r == 0 && tid == 0) offs[N] = E;
  __syncthreads();
  for (int i = S + tid; i < S1; i += 1024) {
    int e = ebuf[i];
    srt[atomicAdd(&hist[e >> 16], 1)] = (ushort)(e & 0xFFFF);
  }
}

// ---------------- dense transform: Gb = bf16((X @ W) * dinv[row]) ----------------
// Unroll capped at 4 to avoid the round-1 VGPR blowup (256 VGPR + 380MB scratch spill).

template <int K, int ROWS>
__global__ __launch_bounds__(256) void gemm_scale(
    const float* __restrict__ X, const float* __restrict__ W,
    const float* __restrict__ dinv, ushort* __restrict__ Gb, int N) {
  __shared__ float smw[K * 64];
  __shared__ float xs[ROWS * K];
  int tid = threadIdx.x, lane = tid & 63, wv = tid >> 6;
  for (int idx = tid; idx < K * 16; idx += 256)
    ((float4*)smw)[idx] = ((const float4*)W)[idx];
  int row0 = blockIdx.x * ROWS;
  int base = row0 * K;
  int cnt4 = (min(ROWS * K, N * K - base)) >> 2;  // K%4==0 so exact
  const float4* X4 = (const float4*)(X + base);
  for (int idx = tid; idx < cnt4; idx += 256) ((float4*)xs)[idx] = X4[idx];
  __syncthreads();

  constexpr int RW = ROWS / 4;  // rows per wave
  float acc[RW];
#pragma unroll
  for (int r = 0; r < RW; ++r) acc[r] = 0.f;
  const float* xr = &xs[(wv * RW) * K];
#pragma unroll 4
  for (int k = 0; k < K; ++k) {
    float wval = smw[k * 64 + lane];  // lane-contiguous: 2-way bank alias = free
#pragma unroll
    for (int r = 0; r < RW; ++r) acc[r] = fmaf(xr[r * K + k], wval, acc[r]);  // LDS broadcast
  }
#pragma unroll
  for (int r = 0; r < RW; ++r) {
    int row = row0 + wv * RW + r;
    if (row < N) Gb[(size_t)row * 64 + lane] = f32_to_bf16(acc[r] * dinv[row]);
  }
}

// ---------------- aggregation with fused dense epilogue ----------------
// one wave per node (r11 structure: proven-best 47.4us); lane = sub*16 + fl;
// indices hoisted to regs + dynamic shfl; 8 bf16 rows (2 lines) in flight.
// MODE 0 (layer 1): h = relu(acc*dinv + b1); fused h@W2 (16 shfl + 16 L1-hit W2 float4
//   + 64 FMA, butterfly combine); Gout[node] = bf16(out * dinv). gemm2 GONE.
// MODE 1 (layer 2): h = relu(acc*dinv + b2); fused classifier dot -> part[blk][6].

template <int MODE>
__global__ __launch_bounds__(256) void aggregate(
    const ushort* __restrict__ Gb, const int* __restrict__ offs,
    const ushort* __restrict__ srt, const float* __restrict__ dinv,
    const float* __restrict__ bias, const float* __restrict__ Wx,  // W2 (MODE0) / Wc (MODE1)
    ushort* __restrict__ Gout, float* __restrict__ part, int N) {
  int lane = threadIdx.x & 63, wv = threadIdx.x >> 6;
  int sub = lane >> 4, fl = lane & 15;
  int node = blockIdx.x * 4 + wv;
  const ushort4* G2 = (const ushort4*)Gb;  // 16 x ushort4 per 64-feat row

  if (MODE == 0 && node >= N) return;  // MODE1 block-reduce needs all threads

  int e0 = 0, e1 = 0;
  if (node < N) { e0 = offs[node]; e1 = offs[node + 1]; }
  int deg = e1 - e0;

  float4 accA = make_float4(0.f, 0.f, 0.f, 0.f);
  float4 accB = make_float4(0.f, 0.f, 0.f, 0.f);
  if (sub == 0 && node < N) {  // self loop
    ushort4 q = G2[(size_t)node * 16 + fl];
    accA.x = bf16_to_f32(q.x); accA.y = bf16_to_f32(q.y);
    accA.z = bf16_to_f32(q.z); accA.w = bf16_to_f32(q.w);
  }

  // hoist up to 64 edge indices into registers (coalesced ushort; mean deg 16)
  int pre = (deg > 0) ? (int)srt[e0 + min(lane, deg - 1)] : 0;

  int dcap = min(deg, 64);
  int base = 0;
  for (; base + 7 < dcap; base += 8) {   // 8 rows in flight, no index-load chain
    int sA = __shfl(pre, base + sub, 64);
    int sB = __shfl(pre, base + 4 + sub, 64);
    ushort4 qA = G2[(size_t)sA * 16 + fl];
    ushort4 qB = G2[(size_t)sB * 16 + fl];
    accA.x += bf16_to_f32(qA.x); accA.y += bf16_to_f32(qA.y);
    accA.z += bf16_to_f32(qA.z); accA.w += bf16_to_f32(qA.w);
    accB.x += bf16_to_f32(qB.x); accB.y += bf16_to_f32(qB.y);
    accB.z += bf16_to_f32(qB.z); accB.w += bf16_to_f32(qB.w);
  }
  for (; base + 3 < dcap; base += 4) {
    int s = __shfl(pre, base + sub, 64);
    ushort4 q = G2[(size_t)s * 16 + fl];
    accA.x += bf16_to_f32(q.x); accA.y += bf16_to_f32(q.y);
    accA.z += bf16_to_f32(q.z); accA.w += bf16_to_f32(q.w);
  }
  int e = e0 + base;
  for (; e + 3 < e1; e += 4) {           // deg>64 spillover (rare)
    int s = srt[e + sub];
    ushort4 q = G2[(size_t)s * 16 + fl];
    accA.x += bf16_to_f32(q.x); accA.y += bf16_to_f32(q.y);
    accA.z += bf16_to_f32(q.z); accA.w += bf16_to_f32(q.w);
  }
  int rem = e1 - e;                      // 0..3 remainder
  if (sub < rem) {
    int s = srt[e + sub];
    ushort4 q = G2[(size_t)s * 16 + fl];
    accA.x += bf16_to_f32(q.x); accA.y += bf16_to_f32(q.y);
    accA.z += bf16_to_f32(q.z); accA.w += bf16_to_f32(q.w);
  }

  float4 acc;
  acc.x = accA.x + accB.x; acc.y = accA.y + accB.y;
  acc.z = accA.z + accB.z; acc.w = accA.w + accB.w;
#pragma unroll
  for (int m = 16; m < 64; m <<= 1) {
    acc.x += __shfl_xor(acc.x, m, 64);
    acc.y += __shfl_xor(acc.y, m, 64);
    acc.z += __shfl_xor(acc.z, m, 64);
    acc.w += __shfl_xor(acc.w, m, 64);
  }

  if (MODE == 0) {
    // ---- fused gemm2 epilogue: Gout[node] = bf16( relu(acc*dinv+b1) @ W2 * dinv ) ----
    if (node < N) {
      float dn = dinv[node];
      float4 bb = ((const float4*)bias)[fl];
      float4 r;
      r.x = fmaxf(fmaf(acc.x, dn, bb.x), 0.f);
      r.y = fmaxf(fmaf(acc.y, dn, bb.y), 0.f);
      r.z = fmaxf(fmaf(acc.z, dn, bb.z), 0.f);
      r.w = fmaxf(fmaf(acc.w, dn, bb.w), 0.f);
      // sub s handles k in [16s,16s+16): quads g=4s+t held by lane (s, g)
      float4 o = make_float4(0.f, 0.f, 0.f, 0.f);
#pragma unroll
      for (int t = 0; t < 4; ++t) {
        int g = 4 * sub + t;
        int srcl = (lane & 48) | g;     // same sub, lane fl=g holds h quad g
        float h0 = __shfl(r.x, srcl, 64);
        float h1 = __shfl(r.y, srcl, 64);
        float h2 = __shfl(r.z, srcl, 64);
        float h3 = __shfl(r.w, srcl, 64);
        const float* wp = Wx + (size_t)(4 * g) * 64 + 4 * fl;  // W2[k][j], L1-resident 16KB
        float4 w0 = *(const float4*)(wp);
        float4 w1 = *(const float4*)(wp + 64);
        float4 w2 = *(const float4*)(wp + 128);
        float4 w3 = *(const float4*)(wp + 192);
        o.x = fmaf(h0, w0.x, fmaf(h1, w1.x, fmaf(h2, w2.x, fmaf(h3, w3.x, o.x))));
        o.y = fmaf(h0, w0.y, fmaf(h1, w1.y, fmaf(h2, w2.y, fmaf(h3, w3.y, o.y))));
        o.z = fmaf(h0, w0.z, fmaf(h1, w1.z, fmaf(h2, w2.z, fmaf(h3, w3.z, o.z))));
        o.w = fmaf(h0, w0.w, fmaf(h1, w1.w, fmaf(h2, w2.w, fmaf(h3, w3.w, o.w))));
      }
#pragma unroll
      for (int m = 16; m < 64; m <<= 1) {  // combine the 4 k-partitions
        o.x += __shfl_xor(o.x, m, 64);
        o.y += __shfl_xor(o.y, m, 64);
        o.z += __shfl_xor(o.z, m, 64);
        o.w += __shfl_xor(o.w, m, 64);
      }
      if (sub == 0) {
        ushort4 q;
        q.x = f32_to_bf16(o.x * dn);
        q.y = f32_to_bf16(o.y * dn);
        q.z = f32_to_bf16(o.z * dn);
        q.w = f32_to_bf16(o.w * dn);
        ((ushort4*)Gout)[(size_t)node * 16 + fl] = q;
      }
    }
  } else {
    // ---- fused classifier epilogue (r11, verified) ----
    float a[6] = {0.f, 0.f, 0.f, 0.f, 0.f, 0.f};
    if (sub == 0 && node < N) {
      float dn = dinv[node];
      float4 bb = ((const float4*)bias)[fl];
      float4 r;
      r.x = fmaxf(fmaf(acc.x, dn, bb.x), 0.f);
      r.y = fmaxf(fmaf(acc.y, dn, bb.y), 0.f);
      r.z = fmaxf(fmaf(acc.z, dn, bb.z), 0.f);
      r.w = fmaxf(fmaf(acc.w, dn, bb.w), 0.f);
      // Wc slice for feats 4fl..4fl+3 of this node: 24 contiguous floats
      const float4* w4 = (const float4*)(Wx + (size_t)node * 384 + fl * 24);
      float4 w0 = w4[0], w1 = w4[1], w2 = w4[2], w3 = w4[3], w4_ = w4[4], w5 = w4[5];
      // layout: [f0c0..f0c5 f1c0..f1c5 f2c0..f2c5 f3c0..f3c5]
      a[0] = fmaf(r.x, w0.x, fmaf(r.y, w1.z, fmaf(r.z, w3.x, r.w * w4_.z)));
      a[1] = fmaf(r.x, w0.y, fmaf(r.y, w1.w, fmaf(r.z, w3.y, r.w * w4_.w)));
      a[2] = fmaf(r.x, w0.z, fmaf(r.y, w2.x, fmaf(r.z, w3.z, r.w * w5.x)));
      a[3] = fmaf(r.x, w0.w, fmaf(r.y, w2.y, fmaf(r.z, w3.w, r.w * w5.y)));
      a[4] = fmaf(r.x, w1.x, fmaf(r.y, w2.z, fmaf(r.z, w4_.x, r.w * w5.z)));
      a[5] = fmaf(r.x, w1.y, fmaf(r.y, w2.w, fmaf(r.z, w4_.y, r.w * w5.w)));
    }
#pragma unroll
    for (int c = 0; c < 6; ++c) {
      for (int d = 32; d > 0; d >>= 1) a[c] += __shfl_down(a[c], d, 64);
    }
    __shared__ float sh[4][6];
    if (lane == 0) {
#pragma unroll
      for (int c = 0; c < 6; ++c) sh[wv][c] = a[c];
    }
    __syncthreads();
    if (threadIdx.x == 0) {
#pragma unroll
      for (int c = 0; c < 6; ++c)
        part[(size_t)blockIdx.x * 6 + c] = sh[0][c] + sh[1][c] + sh[2][c] + sh[3][c];
    }
  }
}

// single block: sum part[nb][6], add bias, softmax, write out[6]
__global__ __launch_bounds__(1024) void reduce_softmax(
    const float* __restrict__ part, int nb,
    const float* __restrict__ bc, float* __restrict__ out) {
  int tid = threadIdx.x, lane = tid & 63, wv = tid >> 6;
  float a[6] = {0.f, 0.f, 0.f, 0.f, 0.f, 0.f};
  for (int b = tid; b < nb; b += 1024) {
    const float* p = part + (size_t)b * 6;
#pragma unroll
    for (int c = 0; c < 6; ++c) a[c] += p[c];
  }
#pragma unroll
  for (int c = 0; c < 6; ++c) {
    for (int d = 32; d > 0; d >>= 1) a[c] += __shfl_down(a[c], d, 64);
  }
  __shared__ float sh[16][6];
  if (lane == 0) {
#pragma unroll
    for (int c = 0; c < 6; ++c) sh[wv][c] = a[c];
  }
  __syncthreads();
  if (tid == 0) {
    float l[6], m = -1e30f;
#pragma unroll
    for (int c = 0; c < 6; ++c) {
      float t = 0.f;
      for (int w = 0; w < 16; ++w) t += sh[w][c];
      l[c] = t + bc[c];
      m = fmaxf(m, l[c]);
    }
    float s = 0.f;
#pragma unroll
    for (int c = 0; c < 6; ++c) { l[c] = __expf(l[c] - m); s += l[c]; }
    float inv = 1.f / s;
#pragma unroll
    for (int c = 0; c < 6; ++c) out[c] = l[c] * inv;
  }
}

// ---------------- launch ----------------

static inline size_t align4up(size_t x) { return (x + 3) & ~(size_t)3; }  // 4-elem = 16B

extern "C" void kernel_launch(void* const* d_in, const int* in_sizes, int n_in,
                              void* d_out, int out_size, void* d_ws, size_t ws_size,
                              hipStream_t stream) {
  const float* x  = (const float*)d_in[0];
  const int*   ei = (const int*)d_in[1];
  const float* W1 = (const float*)d_in[2];
  const float* b1 = (const float*)d_in[3];
  const float* W2 = (const float*)d_in[4];
  const float* b2 = (const float*)d_in[5];
  const float* Wc = (const float*)d_in[6];
  const float* bc = (const float*)d_in[7];
  float* out = (float*)d_out;

  const int N = in_sizes[0] / 128;  // 50000
  const int E = in_sizes[1] / 2;    // 800000
  const int* esrc = ei;
  const int* edst = ei + E;
  const int NR = (N + (1 << RBITS) - 1) >> RBITS;  // 196 ranges (<= NR_MAX)
  const int AGRID = (N + 3) / 4;                   // 12500 aggregate blocks (1 node/wave)

  // 16B-aligned workspace carve
  size_t o = 0;
  int* offs    = (int*)d_ws + o;            o = align4up(o + N + 1);
  ushort* srt  = (ushort*)((int*)d_ws + o); o = align4up(o + (E + 1) / 2);  // E ushorts
  float* dinv  = (float*)d_ws + o;          o = align4up(o + N);
  int* ghist   = (int*)d_ws + o;            o = align4up(o + (size_t)NR * NCH);
  ushort* Gb1  = (ushort*)((int*)d_ws + o); o = align4up(o + (size_t)N * 32);  // N*64 bf16
  ushort* Gb2  = (ushort*)((int*)d_ws + o); o = align4up(o + max((size_t)N * 32, (size_t)E));
  float* part  = (float*)d_ws + o;          o = align4up(o + (size_t)AGRID * 6);
  int* ebuf    = (int*)Gb2;  // aliases Gb2: ebuf dead after csr_range, Gb2 written by agg1

  hist_ranges<<<NCH, 256, 0, stream>>>(edst, ghist, NR, E);
  scatter_ranges<<<NCH, 256, 0, stream>>>(esrc, edst, ghist, ebuf, NR, E);
  csr_range<<<NR, 1024, 0, stream>>>(ebuf, ghist, offs, srt, dinv, N, E, NR);

  gemm_scale<128, 32><<<(N + 31) / 32, 256, 0, stream>>>(x, W1, dinv, Gb1, N);
  aggregate<0><<<AGRID, 256, 0, stream>>>(Gb1, offs, srt, dinv, b1, W2, Gb2, nullptr, N);
  aggregate<1><<<AGRID, 256, 0, stream>>>(Gb2, offs, srt, dinv, b2, Wc, nullptr, part, N);

  reduce_softmax<<<1, 1024, 0, stream>>>(part, AGRID, bc, out);
}

// Round 16
// 150.769 us; speedup vs baseline: 1.4822x; 1.0460x over previous
//
#include <hip/hip_runtime.h>
#include <math.h>

// SensorGNN: 2-layer GCN (N=50000, E=800000, F=128, H=64) + flat classifier (6 classes).
// Graph build = counting sort by dst-range (RBITS=8, NR=196): hist_ranges ->
//   scatter_ranges(folded scan, packed ebuf) -> csr_range(dinv/offs/ushort srt).
// Compute: gemm1(+dinv->bf16 Gb1) -> agg1(fused h@W2 -> bf16 Gb2) -> agg2(fused classifier)
//   -> reduce+softmax.  7 launches, H never materialized.
// r3: same-line global atomics serialize cross-XCD. r4/5: random atomic scatter bounces
// lines via HBM. r6: edge replication = occupancy loss. r7-r13: six aggregate structures
// all 45-57us. r12 (decisive): half the gathers = same time -> per-node FIXED chain
// (offs->srt->self) dominates. r13: amortizing chain by cutting waves 4x lost (TLP).
// r14/r15: dense epilogues fuse for free; graph build slimmed.
// r16: persistent aggregate -- keep 8192 waves (full 32 waves/CU) AND pipeline the
//   next node's offs/srt chain under the current node's gathers+reduce+epilogue.

#define NCH 256          // edge chunk blocks
#define RBITS 8          // range = 256 nodes
#define NR_MAX 256

__device__ __forceinline__ ushort f32_to_bf16(float f) {  // RTN-even
  unsigned u = __float_as_uint(f);
  return (ushort)((u + 0x7fffu + ((u >> 16) & 1u)) >> 16);
}
__device__ __forceinline__ float bf16_to_f32(ushort h) {
  return __uint_as_float(((unsigned)h) << 16);
}

// ---------------- pass A: per-chunk range histograms (raw counts) ----------------

__global__ __launch_bounds__(256) void hist_ranges(
    const int* __restrict__ dst, int* __restrict__ ghist, int NR, int E) {
  __shared__ int h[NR_MAX];
  int tid = threadIdx.x, c = blockIdx.x;
  for (int i = tid; i < NR; i += 256) h[i] = 0;
  __syncthreads();
  int E4 = E >> 2;
  int CH4 = (E4 + NCH - 1) / NCH;
  int i0 = c * CH4, i1 = min(i0 + CH4, E4);
  const int4* d4 = (const int4*)dst;
  for (int i = i0 + tid; i < i1; i += 256) {
    int4 d = d4[i];
    atomicAdd(&h[d.x >> RBITS], 1);
    atomicAdd(&h[d.y >> RBITS], 1);
    atomicAdd(&h[d.z >> RBITS], 1);
    atomicAdd(&h[d.w >> RBITS], 1);
  }
  if (c == NCH - 1) {
    for (int e = (E4 << 2) + tid; e < E; e += 256) atomicAdd(&h[dst[e] >> RBITS], 1);
  }
  __syncthreads();
  for (int i = tid; i < NR; i += 256) ghist[i * NCH + c] = h[i];  // range-major, chunk-minor
}

// ---------------- pass B: scatter with per-block folded prefix scan ----------------
// ebuf entry = src | ((dst & 255) << 16)  (src < 2^16, dst-lo 8 bits)

__global__ __launch_bounds__(256) void scatter_ranges(
    const int* __restrict__ src, const int* __restrict__ dst,
    const int* __restrict__ ghist, int* __restrict__ ebuf, int NR, int E) {
  __shared__ int cur[NR_MAX];
  __shared__ int rowpre[NR_MAX + 1];
  int tid = threadIdx.x, c = blockIdx.x;
  if (tid < NR) {  // row totals (vectorized over 200KB L2-hot hist)
    const int4* row = (const int4*)(ghist + tid * NCH);
    int s = 0;
    for (int q = 0; q < NCH / 4; ++q) { int4 v = row[q]; s += v.x + v.y + v.z + v.w; }
    rowpre[tid + 1] = s;
  }
  __syncthreads();
  if (tid == 0) {
    rowpre[0] = 0;
    for (int i = 1; i <= NR; ++i) rowpre[i] += rowpre[i - 1];
  }
  __syncthreads();
  if (tid < NR) {  // + chunks < c within own row
    int s = rowpre[tid];
    const int* row = ghist + tid * NCH;
    const int4* row4 = (const int4*)row;
    int c4 = c >> 2;
    for (int q = 0; q < c4; ++q) { int4 v = row4[q]; s += v.x + v.y + v.z + v.w; }
    for (int cc = c4 << 2; cc < c; ++cc) s += row[cc];
    cur[tid] = s;
  }
  __syncthreads();
  int E4 = E >> 2;
  int CH4 = (E4 + NCH - 1) / NCH;
  int i0 = c * CH4, i1 = min(i0 + CH4, E4);
  const int4* d4 = (const int4*)dst;
  const int4* s4 = (const int4*)src;
  for (int i = i0 + tid; i < i1; i += 256) {
    int4 d = d4[i];
    int4 s = s4[i];
    ebuf[atomicAdd(&cur[d.x >> RBITS], 1)] = s.x | ((d.x & 255) << 16);
    ebuf[atomicAdd(&cur[d.y >> RBITS], 1)] = s.y | ((d.y & 255) << 16);
    ebuf[atomicAdd(&cur[d.z >> RBITS], 1)] = s.z | ((d.z & 255) << 16);
    ebuf[atomicAdd(&cur[d.w >> RBITS], 1)] = s.w | ((d.w & 255) << 16);
  }
  if (c == NCH - 1) {
    for (int e = (E4 << 2) + tid; e < E; e += 256)
      ebuf[atomicAdd(&cur[dst[e] >> RBITS], 1)] = src[e] | ((dst[e] & 255) << 16);
  }
}

// ---------------- pass C: per-range CSR build (dinv, offs, ushort srt) ----------------

__global__ __launch_bounds__(1024) void csr_range(
    const int* __restrict__ ebuf, const int* __restrict__ ghist,
    int* __restrict__ offs, ushort* __restrict__ srt, float* __restrict__ dinv,
    int N, int E, int NR) {
  __shared__ int hist[NR_MAX];   // 256 per-node counts -> cursors
  __shared__ int wtot[16];
  __shared__ int rowpre[NR_MAX + 1];
  int r = blockIdx.x;
  int lo = r << RBITS;
  int len = min(1 << RBITS, N - lo);
  int tid = threadIdx.x, lane = tid & 63, wv = tid >> 6;
  if (tid < NR) {
    const int4* row = (const int4*)(ghist + tid * NCH);
    int s = 0;
    for (int q = 0; q < NCH / 4; ++q) { int4 v = row[q]; s += v.x + v.y + v.z + v.w; }
    rowpre[tid + 1] = s;
  }
  if (tid < len) hist[tid] = 0;
  __syncthreads();
  if (tid == 0) {
    rowpre[0] = 0;
    for (int i = 1; i <= NR; ++i) rowpre[i] += rowpre[i - 1];
  }
  __syncthreads();
  int S = rowpre[r], S1 = rowpre[r + 1];
  for (int i = S + tid; i < S1; i += 1024) atomicAdd(&hist[ebuf[i] >> 16], 1);
  __syncthreads();
  int v = (tid < len) ? hist[tid] : 0;
  if (tid < len) dinv[lo + tid] = rsqrtf((float)(v + 1));  // +1 self loop
  // exclusive scan of v across 1024 threads (only first len nonzero)
  int x = v;
#pragma unroll
  for (int d = 1; d < 64; d <<= 1) { int y = __shfl_up(x, d, 64); if (lane >= d) x += y; }
  if (lane == 63) wtot[wv] = x;
  __syncthreads();
  if (wv == 0 && lane < 16) {
    int t = wtot[lane], xx = t;
#pragma unroll
    for (int d = 1; d < 16; d <<= 1) { int y = __shfl_up(xx, d, 64); if (lane >= d) xx += y; }
    wtot[lane] = xx - t;
  }
  __syncthreads();
  int excl = x - v + wtot[wv];
  if (tid < len) {
    offs[lo + tid] = S + excl;
    hist[tid] = S + excl;  // reuse as cursor
  }
  if (r == 0 && tid == 0) offs[N] = E;
  __syncthreads();
  for (int i = S + tid; i < S1; i += 1024) {
    int e = ebuf[i];
    srt[atomicAdd(&hist[e >> 16], 1)] = (ushort)(e & 0xFFFF);
  }
}

// ---------------- dense transform: Gb = bf16((X @ W) * dinv[row]) ----------------
// Unroll capped at 4 to avoid the round-1 VGPR blowup (256 VGPR + 380MB scratch spill).

template <int K, int ROWS>
__global__ __launch_bounds__(256) void gemm_scale(
    const float* __restrict__ X, const float* __restrict__ W,
    const float* __restrict__ dinv, ushort* __restrict__ Gb, int N) {
  __shared__ float smw[K * 64];
  __shared__ float xs[ROWS * K];
  int tid = threadIdx.x, lane = tid & 63, wv = tid >> 6;
  for (int idx = tid; idx < K * 16; idx += 256)
    ((float4*)smw)[idx] = ((const float4*)W)[idx];
  int row0 = blockIdx.x * ROWS;
  int base = row0 * K;
  int cnt4 = (min(ROWS * K, N * K - base)) >> 2;  // K%4==0 so exact
  const float4* X4 = (const float4*)(X + base);
  for (int idx = tid; idx < cnt4; idx += 256) ((float4*)xs)[idx] = X4[idx];
  __syncthreads();

  constexpr int RW = ROWS / 4;  // rows per wave
  float acc[RW];
#pragma unroll
  for (int r = 0; r < RW; ++r) acc[r] = 0.f;
  const float* xr = &xs[(wv * RW) * K];
#pragma unroll 4
  for (int k = 0; k < K; ++k) {
    float wval = smw[k * 64 + lane];  // lane-contiguous: 2-way bank alias = free
#pragma unroll
    for (int r = 0; r < RW; ++r) acc[r] = fmaf(xr[r * K + k], wval, acc[r]);  // LDS broadcast
  }
#pragma unroll
  for (int r = 0; r < RW; ++r) {
    int row = row0 + wv * RW + r;
    if (row < N) Gb[(size_t)row * 64 + lane] = f32_to_bf16(acc[r] * dinv[row]);
  }
}

// ---------------- persistent aggregation with cross-node pipelining ----------------
// 2048 blocks x 4 waves = 8192 waves = exactly 32 waves/CU (full occupancy).
// Each wave grid-strides nodes (~6 each). Per iteration: prefetch offs[n+NW] BEFORE the
// current gathers; prefetch srt hoist for n+NW after the gathers (lands during
// reduce+epilogue). The per-node fixed chain (r12's diagnosed limiter) overlaps the
// previous node's compute instead of serializing.
// MODE 0: h=relu(acc*dinv+b1); fused h@W2; Gout=bf16(out*dinv).  (gemm2 fused, r14)
// MODE 1: h=relu(acc*dinv+b2); fused classifier into per-thread cls[6], block-reduced
//         ONCE after the node loop -> part[blk][6].  (r11 fusion, loop-hoisted)

template <int MODE>
__global__ __launch_bounds__(256) void aggregate(
    const ushort* __restrict__ Gb, const int* __restrict__ offs,
    const ushort* __restrict__ srt, const float* __restrict__ dinv,
    const float* __restrict__ bias, const float* __restrict__ Wx,  // W2 (MODE0) / Wc (MODE1)
    ushort* __restrict__ Gout, float* __restrict__ part, int N, int NW) {
  int lane = threadIdx.x & 63, wv = threadIdx.x >> 6;
  int sub = lane >> 4, fl = lane & 15;
  const ushort4* G2 = (const ushort4*)Gb;

  float cls[6] = {0.f, 0.f, 0.f, 0.f, 0.f, 0.f};  // MODE1 per-thread logit partials
  float4 bb = ((const float4*)bias)[fl];           // loop-invariant

  int node = blockIdx.x * 4 + wv;                  // < 8192 <= N always valid
  int e0 = offs[node], e1 = offs[node + 1];
  {
    int dg = e1 - e0;
    e0 = e0; e1 = e1;
  }
  int pre;
  {
    int dg = e1 - e0;
    pre = (dg > 0) ? (int)srt[e0 + min(lane, dg - 1)] : 0;
  }

  while (true) {
    // ---- prefetch next node's offsets (latency hides under gathers below) ----
    int nnode = node + NW;
    bool nvalid = nnode < N;
    int ne0 = 0, ne1 = 0;
    if (nvalid) { ne0 = offs[nnode]; ne1 = offs[nnode + 1]; }

    int deg = e1 - e0;
    float4 accA = make_float4(0.f, 0.f, 0.f, 0.f);
    float4 accB = make_float4(0.f, 0.f, 0.f, 0.f);
    if (sub == 0) {  // self loop
      ushort4 q = G2[(size_t)node * 16 + fl];
      accA.x = bf16_to_f32(q.x); accA.y = bf16_to_f32(q.y);
      accA.z = bf16_to_f32(q.z); accA.w = bf16_to_f32(q.w);
    }

    int dcap = min(deg, 64);
    int base = 0;
    for (; base + 7 < dcap; base += 8) {   // 8 rows in flight
      int sA = __shfl(pre, base + sub, 64);
      int sB = __shfl(pre, base + 4 + sub, 64);
      ushort4 qA = G2[(size_t)sA * 16 + fl];
      ushort4 qB = G2[(size_t)sB * 16 + fl];
      accA.x += bf16_to_f32(qA.x); accA.y += bf16_to_f32(qA.y);
      accA.z += bf16_to_f32(qA.z); accA.w += bf16_to_f32(qA.w);
      accB.x += bf16_to_f32(qB.x); accB.y += bf16_to_f32(qB.y);
      accB.z += bf16_to_f32(qB.z); accB.w += bf16_to_f32(qB.w);
    }
    for (; base + 3 < dcap; base += 4) {
      int s = __shfl(pre, base + sub, 64);
      ushort4 q = G2[(size_t)s * 16 + fl];
      accA.x += bf16_to_f32(q.x); accA.y += bf16_to_f32(q.y);
      accA.z += bf16_to_f32(q.z); accA.w += bf16_to_f32(q.w);
    }
    int e = e0 + base;
    for (; e + 3 < e1; e += 4) {           // deg>64 spillover (rare)
      int s = srt[e + sub];
      ushort4 q = G2[(size_t)s * 16 + fl];
      accA.x += bf16_to_f32(q.x); accA.y += bf16_to_f32(q.y);
      accA.z += bf16_to_f32(q.z); accA.w += bf16_to_f32(q.w);
    }
    int rem = e1 - e;                      // 0..3 remainder
    if (sub < rem) {
      int s = srt[e + sub];
      ushort4 q = G2[(size_t)s * 16 + fl];
      accA.x += bf16_to_f32(q.x); accA.y += bf16_to_f32(q.y);
      accA.z += bf16_to_f32(q.z); accA.w += bf16_to_f32(q.w);
    }

    // ---- prefetch next node's srt hoist (lands during reduce+epilogue) ----
    int npre = 0;
    if (nvalid) {
      int nd = ne1 - ne0;
      npre = (nd > 0) ? (int)srt[ne0 + min(lane, nd - 1)] : 0;
    }

    float4 acc;
    acc.x = accA.x + accB.x; acc.y = accA.y + accB.y;
    acc.z = accA.z + accB.z; acc.w = accA.w + accB.w;
#pragma unroll
    for (int m = 16; m < 64; m <<= 1) {
      acc.x += __shfl_xor(acc.x, m, 64);
      acc.y += __shfl_xor(acc.y, m, 64);
      acc.z += __shfl_xor(acc.z, m, 64);
      acc.w += __shfl_xor(acc.w, m, 64);
    }

    float dn = dinv[node];
    if (MODE == 0) {
      // ---- fused gemm2 epilogue: Gout[node] = bf16( relu(acc*dn+b1) @ W2 * dn ) ----
      float4 r;
      r.x = fmaxf(fmaf(acc.x, dn, bb.x), 0.f);
      r.y = fmaxf(fmaf(acc.y, dn, bb.y), 0.f);
      r.z = fmaxf(fmaf(acc.z, dn, bb.z), 0.f);
      r.w = fmaxf(fmaf(acc.w, dn, bb.w), 0.f);
      float4 o = make_float4(0.f, 0.f, 0.f, 0.f);
#pragma unroll
      for (int t = 0; t < 4; ++t) {
        int g = 4 * sub + t;
        int srcl = (lane & 48) | g;     // same sub, lane fl=g holds h quad g
        float h0 = __shfl(r.x, srcl, 64);
        float h1 = __shfl(r.y, srcl, 64);
        float h2 = __shfl(r.z, srcl, 64);
        float h3 = __shfl(r.w, srcl, 64);
        const float* wp = Wx + (size_t)(4 * g) * 64 + 4 * fl;  // W2 16KB, L1-resident
        float4 w0 = *(const float4*)(wp);
        float4 w1 = *(const float4*)(wp + 64);
        float4 w2 = *(const float4*)(wp + 128);
        float4 w3 = *(const float4*)(wp + 192);
        o.x = fmaf(h0, w0.x, fmaf(h1, w1.x, fmaf(h2, w2.x, fmaf(h3, w3.x, o.x))));
        o.y = fmaf(h0, w0.y, fmaf(h1, w1.y, fmaf(h2, w2.y, fmaf(h3, w3.y, o.y))));
        o.z = fmaf(h0, w0.z, fmaf(h1, w1.z, fmaf(h2, w2.z, fmaf(h3, w3.z, o.z))));
        o.w = fmaf(h0, w0.w, fmaf(h1, w1.w, fmaf(h2, w2.w, fmaf(h3, w3.w, o.w))));
      }
#pragma unroll
      for (int m = 16; m < 64; m <<= 1) {  // combine the 4 k-partitions
        o.x += __shfl_xor(o.x, m, 64);
        o.y += __shfl_xor(o.y, m, 64);
        o.z += __shfl_xor(o.z, m, 64);
        o.w += __shfl_xor(o.w, m, 64);
      }
      if (sub == 0) {
        ushort4 q;
        q.x = f32_to_bf16(o.x * dn);
        q.y = f32_to_bf16(o.y * dn);
        q.z = f32_to_bf16(o.z * dn);
        q.w = f32_to_bf16(o.w * dn);
        ((ushort4*)Gout)[(size_t)node * 16 + fl] = q;
      }
    } else {
      // ---- fused classifier: accumulate into per-thread cls[6] ----
      if (sub == 0) {
        float4 r;
        r.x = fmaxf(fmaf(acc.x, dn, bb.x), 0.f);
        r.y = fmaxf(fmaf(acc.y, dn, bb.y), 0.f);
        r.z = fmaxf(fmaf(acc.z, dn, bb.z), 0.f);
        r.w = fmaxf(fmaf(acc.w, dn, bb.w), 0.f);
        const float4* w4 = (const float4*)(Wx + (size_t)node * 384 + fl * 24);
        float4 w0 = w4[0], w1 = w4[1], w2 = w4[2], w3 = w4[3], w4_ = w4[4], w5 = w4[5];
        // layout: [f0c0..f0c5 f1c0..f1c5 f2c0..f2c5 f3c0..f3c5]
        cls[0] = fmaf(r.x, w0.x, fmaf(r.y, w1.z, fmaf(r.z, w3.x, fmaf(r.w, w4_.z, cls[0]))));
        cls[1] = fmaf(r.x, w0.y, fmaf(r.y, w1.w, fmaf(r.z, w3.y, fmaf(r.w, w4_.w, cls[1]))));
        cls[2] = fmaf(r.x, w0.z, fmaf(r.y, w2.x, fmaf(r.z, w3.z, fmaf(r.w, w5.x, cls[2]))));
        cls[3] = fmaf(r.x, w0.w, fmaf(r.y, w2.y, fmaf(r.z, w3.w, fmaf(r.w, w5.y, cls[3]))));
        cls[4] = fmaf(r.x, w1.x, fmaf(r.y, w2.z, fmaf(r.z, w4_.x, fmaf(r.w, w5.z, cls[4]))));
        cls[5] = fmaf(r.x, w1.y, fmaf(r.y, w2.w, fmaf(r.z, w4_.y, fmaf(r.w, w5.w, cls[5]))));
      }
    }

    if (!nvalid) break;
    node = nnode; e0 = ne0; e1 = ne1; pre = npre;
  }

  if (MODE == 1) {  // block reduce cls -> part[blk][6], once per kernel
#pragma unroll
    for (int c = 0; c < 6; ++c) {
      for (int d = 32; d > 0; d >>= 1) cls[c] += __shfl_down(cls[c], d, 64);
    }
    __shared__ float sh[4][6];
    if (lane == 0) {
#pragma unroll
      for (int c = 0; c < 6; ++c) sh[wv][c] = cls[c];
    }
    __syncthreads();
    if (threadIdx.x == 0) {
#pragma unroll
      for (int c = 0; c < 6; ++c)
        part[(size_t)blockIdx.x * 6 + c] = sh[0][c] + sh[1][c] + sh[2][c] + sh[3][c];
    }
  }
}

// single block: sum part[nb][6], add bias, softmax, write out[6]
__global__ __launch_bounds__(1024) void reduce_softmax(
    const float* __restrict__ part, int nb,
    const float* __restrict__ bc, float* __restrict__ out) {
  int tid = threadIdx.x, lane = tid & 63, wv = tid >> 6;
  float a[6] = {0.f, 0.f, 0.f, 0.f, 0.f, 0.f};
  for (int b = tid; b < nb; b += 1024) {
    const float* p = part + (size_t)b * 6;
#pragma unroll
    for (int c = 0; c < 6; ++c) a[c] += p[c];
  }
#pragma unroll
  for (int c = 0; c < 6; ++c) {
    for (int d = 32; d > 0; d >>= 1) a[c] += __shfl_down(a[c], d, 64);
  }
  __shared__ float sh[16][6];
  if (lane == 0) {
#pragma unroll
    for (int c = 0; c < 6; ++c) sh[wv][c] = a[c];
  }
  __syncthreads();
  if (tid == 0) {
    float l[6], m = -1e30f;
#pragma unroll
    for (int c = 0; c < 6; ++c) {
      float t = 0.f;
      for (int w = 0; w < 16; ++w) t += sh[w][c];
      l[c] = t + bc[c];
      m = fmaxf(m, l[c]);
    }
    float s = 0.f;
#pragma unroll
    for (int c = 0; c < 6; ++c) { l[c] = __expf(l[c] - m); s += l[c]; }
    float inv = 1.f / s;
#pragma unroll
    for (int c = 0; c < 6; ++c) out[c] = l[c] * inv;
  }
}

// ---------------- launch ----------------

static inline size_t align4up(size_t x) { return (x + 3) & ~(size_t)3; }  // 4-elem = 16B

extern "C" void kernel_launch(void* const* d_in, const int* in_sizes, int n_in,
                              void* d_out, int out_size, void* d_ws, size_t ws_size,
                              hipStream_t stream) {
  const float* x  = (const float*)d_in[0];
  const int*   ei = (const int*)d_in[1];
  const float* W1 = (const float*)d_in[2];
  const float* b1 = (const float*)d_in[3];
  const float* W2 = (const float*)d_in[4];
  const float* b2 = (const float*)d_in[5];
  const float* Wc = (const float*)d_in[6];
  const float* bc = (const float*)d_in[7];
  float* out = (float*)d_out;

  const int N = in_sizes[0] / 128;  // 50000
  const int E = in_sizes[1] / 2;    // 800000
  const int* esrc = ei;
  const int* edst = ei + E;
  const int NR = (N + (1 << RBITS) - 1) >> RBITS;  // 196 ranges (<= NR_MAX)
  const int AGRID = 2048;                          // persistent: 8 blocks/CU, 32 waves/CU
  const int NW = AGRID * 4;                        // 8192 waves grid-striding nodes

  // 16B-aligned workspace carve
  size_t o = 0;
  int* offs    = (int*)d_ws + o;            o = align4up(o + N + 1);
  ushort* srt  = (ushort*)((int*)d_ws + o); o = align4up(o + (E + 1) / 2);  // E ushorts
  float* dinv  = (float*)d_ws + o;          o = align4up(o + N);
  int* ghist   = (int*)d_ws + o;            o = align4up(o + (size_t)NR * NCH);
  ushort* Gb1  = (ushort*)((int*)d_ws + o); o = align4up(o + (size_t)N * 32);  // N*64 bf16
  ushort* Gb2  = (ushort*)((int*)d_ws + o); o = align4up(o + max((size_t)N * 32, (size_t)E));
  float* part  = (float*)d_ws + o;          o = align4up(o + (size_t)AGRID * 6);
  int* ebuf    = (int*)Gb2;  // aliases Gb2: ebuf dead after csr_range, Gb2 written by agg1

  hist_ranges<<<NCH, 256, 0, stream>>>(edst, ghist, NR, E);
  scatter_ranges<<<NCH, 256, 0, stream>>>(esrc, edst, ghist, ebuf, NR, E);
  csr_range<<<NR, 1024, 0, stream>>>(ebuf, ghist, offs, srt, dinv, N, E, NR);

  gemm_scale<128, 32><<<(N + 31) / 32, 256, 0, stream>>>(x, W1, dinv, Gb1, N);
  aggregate<0><<<AGRID, 256, 0, stream>>>(Gb1, offs, srt, dinv, b1, W2, Gb2, nullptr, N, NW);
  aggregate<1><<<AGRID, 256, 0, stream>>>(Gb2, offs, srt, dinv, b2, Wc, nullptr, part, N, NW);

  reduce_softmax<<<1, 1024, 0, stream>>>(part, AGRID, bc, out);
}